// Round 5
// baseline (342.758 us; speedup 1.0000x reference)
//
#include <hip/hip_runtime.h>
#include <hip/hip_bf16.h>
#include <hip/hip_fp16.h>
#include <cstdint>

// Dims
constexpr int B_ = 4, H_ = 16, S_ = 1024, D_ = 1024, DK_ = 64;

typedef __bf16 bf16x8 __attribute__((ext_vector_type(8)));
typedef float f32x4 __attribute__((ext_vector_type(4)));
#define MFMA16(a, b, c) __builtin_amdgcn_mfma_f32_16x16x32_bf16(a, b, c, 0, 0, 0)

static __device__ inline unsigned short f2bf(float f) {
  __hip_bfloat16 h = __float2bfloat16(f);
  return *reinterpret_cast<unsigned short*>(&h);
}
static __device__ inline unsigned packbf(float lo, float hi) {
  return ((unsigned)f2bf(hi) << 16) | (unsigned)f2bf(lo);
}

// ---------------------------------------------------------------------------
// f32 -> bf16 conversions, fused launches
// ---------------------------------------------------------------------------
__global__ __launch_bounds__(256) void k_cvt3(const float* __restrict__ x0,
                                              const float* __restrict__ x1,
                                              const float* __restrict__ x2,
                                              __hip_bfloat16* __restrict__ y0,
                                              __hip_bfloat16* __restrict__ y1,
                                              __hip_bfloat16* __restrict__ y2) {
  const int sel = blockIdx.x >> 12;                       // 4096 blocks per tensor
  const int i = (blockIdx.x & 4095) * 256 + threadIdx.x;  // float4 index
  const float* x = sel == 0 ? x0 : (sel == 1 ? x1 : x2);
  __hip_bfloat16* y = sel == 0 ? y0 : (sel == 1 ? y1 : y2);
  const float4 v = reinterpret_cast<const float4*>(x)[i];
  ushort4 o;
  o.x = f2bf(v.x); o.y = f2bf(v.y); o.z = f2bf(v.z); o.w = f2bf(v.w);
  *reinterpret_cast<ushort4*>(&y[(size_t)i * 4]) = o;
}

__global__ __launch_bounds__(256) void k_cvt4(const float* __restrict__ x0,
                                              const float* __restrict__ x1,
                                              const float* __restrict__ x2,
                                              const float* __restrict__ x3,
                                              __hip_bfloat16* __restrict__ y0,
                                              __hip_bfloat16* __restrict__ y1,
                                              __hip_bfloat16* __restrict__ y2,
                                              __hip_bfloat16* __restrict__ y3) {
  const int sel = blockIdx.x >> 10;                       // 1024 blocks per tensor
  const int i = (blockIdx.x & 1023) * 256 + threadIdx.x;  // float4 index
  const float* x = sel == 0 ? x0 : (sel == 1 ? x1 : (sel == 2 ? x2 : x3));
  __hip_bfloat16* y = sel == 0 ? y0 : (sel == 1 ? y1 : (sel == 2 ? y2 : y3));
  const float4 v = reinterpret_cast<const float4*>(x)[i];
  ushort4 o;
  o.x = f2bf(v.x); o.y = f2bf(v.y); o.z = f2bf(v.z); o.w = f2bf(v.w);
  *reinterpret_cast<ushort4*>(&y[(size_t)i * 4]) = o;
}

// ---------------------------------------------------------------------------
// bf16 MFMA GEMM: C[m,t_tile] = A[m,:] . Bw[t,:]  (A 4096x1024, Bw 1024x1024)
// BM=128, BN=64, BK=64, 256 threads (4 waves, 2x2), per wave 64x32 output.
// LDS chunk-XOR swizzle (16B chunks, chunk^=(row&7)); staged via
// global_load_lds width-16 with pre-swizzled GLOBAL source (linear LDS dest).
// MODE 0: Y bf16 [bh][s][dk], rows m = s*B+b, head = ct
// MODE 1: Y bf16 [bh][dk][s] (transposed; for V)
// MODE 2: Y f32 Z[m][o] = acc + resid[s*B+b][o], rows m = b*S+s
// ---------------------------------------------------------------------------
template <int MODE>
__global__ __launch_bounds__(256) void k_gemm(const __hip_bfloat16* __restrict__ A,
                                              const __hip_bfloat16* __restrict__ Bw,
                                              const float* __restrict__ resid,
                                              __hip_bfloat16* __restrict__ Yb,
                                              float* __restrict__ Yf) {
  __shared__ __hip_bfloat16 Als[128 * 64];
  __shared__ __hip_bfloat16 Bls[64 * 64];
  const int tid = threadIdx.x;
  const int lane = tid & 63;
  const int l15 = lane & 15, g = lane >> 4;
  const int w = tid >> 6;
  const int wr = w >> 1, wc = w & 1;
  const int rt = blockIdx.x, ct = blockIdx.y;
  f32x4 acc[4][2] = {};

  for (int k0 = 0; k0 < D_; k0 += 64) {
    // A: 128 rows x 8 chunks(16B); lds slot s holds global chunk (s&7)^(r&7)
#pragma unroll
    for (int q = 0; q < 4; ++q) {
      const int slot0 = q * 256 + (tid & 192);  // wave-uniform base slot
      const int slot = slot0 + lane;
      const int r = slot >> 3, p = slot & 7;
      const int lc = p ^ (r & 7);
      const __hip_bfloat16* src = A + (size_t)(rt * 128 + r) * D_ + k0 + lc * 8;
      __builtin_amdgcn_global_load_lds(
          (const __attribute__((address_space(1))) unsigned int*)src,
          (__attribute__((address_space(3))) unsigned int*)&Als[slot0 * 8], 16, 0, 0);
    }
#pragma unroll
    for (int q = 0; q < 2; ++q) {
      const int slot0 = q * 256 + (tid & 192);
      const int slot = slot0 + lane;
      const int r = slot >> 3, p = slot & 7;
      const int lc = p ^ (r & 7);
      const __hip_bfloat16* src = Bw + (size_t)(ct * 64 + r) * D_ + k0 + lc * 8;
      __builtin_amdgcn_global_load_lds(
          (const __attribute__((address_space(1))) unsigned int*)src,
          (__attribute__((address_space(3))) unsigned int*)&Bls[slot0 * 8], 16, 0, 0);
    }
    __syncthreads();
#pragma unroll
    for (int ks = 0; ks < 2; ++ks) {
      bf16x8 bfr[2];
#pragma unroll
      for (int cf = 0; cf < 2; ++cf) {
        const int r = wc * 32 + cf * 16 + l15;
        const int p = (ks * 4 + g) ^ (r & 7);
        bfr[cf] = *reinterpret_cast<const bf16x8*>(&Bls[(r * 8 + p) * 8]);
      }
#pragma unroll
      for (int fi = 0; fi < 4; ++fi) {
        const int r = wr * 64 + fi * 16 + l15;
        const int p = (ks * 4 + g) ^ (r & 7);
        const bf16x8 af = *reinterpret_cast<const bf16x8*>(&Als[(r * 8 + p) * 8]);
        acc[fi][0] = MFMA16(af, bfr[0], acc[fi][0]);
        acc[fi][1] = MFMA16(af, bfr[1], acc[fi][1]);
      }
    }
    __syncthreads();
  }
  // epilogue: D-frag col=l15 (B row t), row=4g+reg (A row m)
#pragma unroll
  for (int fi = 0; fi < 4; ++fi)
#pragma unroll
    for (int cf = 0; cf < 2; ++cf)
#pragma unroll
      for (int r = 0; r < 4; ++r) {
        const int m = rt * 128 + wr * 64 + fi * 16 + 4 * g + r;
        const int t = wc * 32 + cf * 16 + l15;
        const float val = acc[fi][cf][r];
        if (MODE == 0) {
          const int s = m >> 2, b = m & 3;
          Yb[((size_t)((b * H_ + ct) * S_ + s)) * DK_ + t] = __float2bfloat16(val);
        } else if (MODE == 1) {
          const int s = m >> 2, b = m & 3;
          Yb[((size_t)((b * H_ + ct) * DK_ + t)) * S_ + s] = __float2bfloat16(val);
        } else {
          const int b = m >> 10, s = m & 1023;
          const int o = ct * 64 + t;
          Yf[(size_t)m * D_ + o] = val + resid[(size_t)(s * B_ + b) * D_ + o];
        }
      }
}

// ---------------------------------------------------------------------------
// Fused attention: per block = 16 query rows of one (b,h).
// Register-resident logits/softmax (no f16 LDS round-trip):
//   Wave w owns keys w*256..w*256+255. mfma(K,Q) gives D[key][query] with
//   col = query = l15 -> each lane's 64 f32 logits ALL belong to row l15.
//   Softmax: 64-reg local reduce + shfl_xor(16,32) + 4x16 LDS cross-wave.
//   One pass writes P f32 (d_out) and bf16 pairs (LDS, XOR-swizzled) for PV.
// Phase 3 (PV): wave w owns outdims w*16..+15; O = mfma(P, V^T-frags).
// ---------------------------------------------------------------------------
__global__ __launch_bounds__(256) void k_attn(const __hip_bfloat16* __restrict__ Qh,
                                              const __hip_bfloat16* __restrict__ Kh,
                                              const __hip_bfloat16* __restrict__ VT,
                                              const float* __restrict__ sph,
                                              float* __restrict__ Pout,
                                              __hip_bfloat16* __restrict__ O) {
  __shared__ unsigned int Plds[16 * 512];  // 32KB bf16-pair P
  __shared__ float redm[4][16];
  __shared__ float reds[4][16];
  const int tid = threadIdx.x, lane = tid & 63, w = tid >> 6;
  const int l15 = lane & 15, g = lane >> 4;
  const int it = blockIdx.x, bh = blockIdx.y;
  const unsigned sw = (unsigned)((l15 & 7) << 2);

  // ---- phase 1: logits in registers (wave w: keys w*256..+255) ----
  f32x4 v0[8], v1[8];
  {
    const __hip_bfloat16* qp = Qh + ((size_t)bh * S_ + it * 16 + l15) * DK_ + 8 * g;
    const bf16x8 qf0 = *reinterpret_cast<const bf16x8*>(qp);
    const bf16x8 qf1 = *reinterpret_cast<const bf16x8*>(qp + 32);
    const float* sprow = sph + ((size_t)bh << 20) + (((size_t)(it * 16 + l15)) << 10);
#pragma unroll
    for (int j = 0; j < 8; ++j) {
      const int key0 = w * 256 + j * 32;
      const __hip_bfloat16* kp = Kh + ((size_t)bh * S_ + key0 + l15) * DK_ + 8 * g;
      const bf16x8 kf0a = *reinterpret_cast<const bf16x8*>(kp);
      const bf16x8 kf0b = *reinterpret_cast<const bf16x8*>(kp + 32);
      const bf16x8 kf1a = *reinterpret_cast<const bf16x8*>(kp + 16 * DK_);
      const bf16x8 kf1b = *reinterpret_cast<const bf16x8*>(kp + 16 * DK_ + 32);
      const float4 s0 = *reinterpret_cast<const float4*>(sprow + key0 + 4 * g);
      const float4 s1 = *reinterpret_cast<const float4*>(sprow + key0 + 16 + 4 * g);
      f32x4 a0 = {0.f, 0.f, 0.f, 0.f};
      f32x4 a1 = {0.f, 0.f, 0.f, 0.f};
      __builtin_amdgcn_s_setprio(1);
      a0 = MFMA16(kf0a, qf0, a0);
      a0 = MFMA16(kf0b, qf1, a0);
      a1 = MFMA16(kf1a, qf0, a1);
      a1 = MFMA16(kf1b, qf1, a1);
      __builtin_amdgcn_s_setprio(0);
      v0[j][0] = a0[0] * 0.125f * s0.x;
      v0[j][1] = a0[1] * 0.125f * s0.y;
      v0[j][2] = a0[2] * 0.125f * s0.z;
      v0[j][3] = a0[3] * 0.125f * s0.w;
      v1[j][0] = a1[0] * 0.125f * s1.x;
      v1[j][1] = a1[1] * 0.125f * s1.y;
      v1[j][2] = a1[2] * 0.125f * s1.z;
      v1[j][3] = a1[3] * 0.125f * s1.w;
    }
  }
  // ---- softmax on registers (row = l15 for every value this lane holds) ----
  float m = v0[0][0];
#pragma unroll
  for (int j = 0; j < 8; ++j)
#pragma unroll
    for (int r = 0; r < 4; ++r) {
      m = fmaxf(m, v0[j][r]);
      m = fmaxf(m, v1[j][r]);
    }
  m = fmaxf(m, __shfl_xor(m, 16));
  m = fmaxf(m, __shfl_xor(m, 32));
  if (lane < 16) redm[w][l15] = m;
  __syncthreads();
  m = fmaxf(fmaxf(redm[0][l15], redm[1][l15]), fmaxf(redm[2][l15], redm[3][l15]));
  float sum = 0.f;
#pragma unroll
  for (int j = 0; j < 8; ++j)
#pragma unroll
    for (int r = 0; r < 4; ++r) {
      v0[j][r] = __expf(v0[j][r] - m);
      v1[j][r] = __expf(v1[j][r] - m);
      sum += v0[j][r] + v1[j][r];
    }
  sum += __shfl_xor(sum, 16);
  sum += __shfl_xor(sum, 32);
  if (lane < 16) reds[w][l15] = sum;
  __syncthreads();
  const float inv =
      1.f / (reds[0][l15] + reds[1][l15] + reds[2][l15] + reds[3][l15]);
  // ---- write P f32 to d_out + bf16 pairs to LDS ----
  {
    float* prow = Pout + ((size_t)bh << 20) + (((size_t)(it * 16 + l15)) << 10);
#pragma unroll
    for (int j = 0; j < 8; ++j) {
      const int key0 = w * 256 + j * 32;
      float4 o0, o1;
      o0.x = v0[j][0] * inv; o0.y = v0[j][1] * inv;
      o0.z = v0[j][2] * inv; o0.w = v0[j][3] * inv;
      o1.x = v1[j][0] * inv; o1.y = v1[j][1] * inv;
      o1.z = v1[j][2] * inv; o1.w = v1[j][3] * inv;
      *reinterpret_cast<float4*>(prow + key0 + 4 * g) = o0;
      *reinterpret_cast<float4*>(prow + key0 + 16 + 4 * g) = o1;
      uint2 u0, u1;
      u0.x = packbf(o0.x, o0.y); u0.y = packbf(o0.z, o0.w);
      u1.x = packbf(o1.x, o1.y); u1.y = packbf(o1.z, o1.w);
      const int base0 = l15 * 512 + (key0 >> 1) + 2 * g;  // pair index
      *reinterpret_cast<uint2*>(&Plds[(unsigned)base0 ^ sw]) = u0;
      *reinterpret_cast<uint2*>(&Plds[(unsigned)(base0 + 8) ^ sw]) = u1;
    }
  }
  __syncthreads();

  // ---- phase 3: PV (wave w: outdims w*16 .. w*16+15) ----
  {
    const int c0 = w * 16;
    f32x4 o0 = {0.f, 0.f, 0.f, 0.f};
    const __hip_bfloat16* vb =
        VT + (size_t)bh * DK_ * S_ + (size_t)(c0 + l15) * S_ + 8 * g;
#pragma unroll 8
    for (int k0 = 0; k0 < S_; k0 += 32) {
      const bf16x8 pa = *reinterpret_cast<const bf16x8*>(
          &Plds[(unsigned)(l15 * 512 + (k0 >> 1) + 4 * g) ^ sw]);
      const bf16x8 vb0 = *reinterpret_cast<const bf16x8*>(vb + k0);
      __builtin_amdgcn_s_setprio(1);
      o0 = MFMA16(pa, vb0, o0);
      __builtin_amdgcn_s_setprio(0);
    }
    const int b = bh >> 4, h = bh & 15;
#pragma unroll
    for (int r = 0; r < 4; ++r) {
      const int srow = it * 16 + 4 * g + r;
      O[((size_t)(b * S_ + srow)) * D_ + h * DK_ + c0 + l15] = __float2bfloat16(o0[r]);
    }
  }
}

// ---------------------------------------------------------------------------
// LayerNorm over D, write [S,B,D]
// ---------------------------------------------------------------------------
__global__ __launch_bounds__(256) void k_ln(const float* __restrict__ Z,
                                            const float* __restrict__ gamma,
                                            const float* __restrict__ beta,
                                            float* __restrict__ out) {
  const int r = blockIdx.x;  // b*S+s
  const int b = r >> 10, s = r & 1023;
  const int tid = threadIdx.x;
  const float4 z = *reinterpret_cast<const float4*>(Z + (size_t)r * D_ + (tid << 2));
  float sum = z.x + z.y + z.z + z.w;
  float sq = z.x * z.x + z.y * z.y + z.z * z.z + z.w * z.w;
#pragma unroll
  for (int off = 1; off < 64; off <<= 1) {
    sum += __shfl_xor(sum, off);
    sq += __shfl_xor(sq, off);
  }
  __shared__ float rs[4];
  __shared__ float rq[4];
  const int wv = tid >> 6, ln = tid & 63;
  if (ln == 0) { rs[wv] = sum; rq[wv] = sq; }
  __syncthreads();
  const float tsum = rs[0] + rs[1] + rs[2] + rs[3];
  const float tsq = rq[0] + rq[1] + rq[2] + rq[3];
  const float mu = tsum * (1.0f / 1024.0f);
  const float var = tsq * (1.0f / 1024.0f) - mu * mu;
  const float rstd = rsqrtf(var + 1e-6f);
  const float4 gm = *reinterpret_cast<const float4*>(gamma + (tid << 2));
  const float4 bt = *reinterpret_cast<const float4*>(beta + (tid << 2));
  float4 o;
  o.x = (z.x - mu) * rstd * gm.x + bt.x;
  o.y = (z.y - mu) * rstd * gm.y + bt.y;
  o.z = (z.z - mu) * rstd * gm.z + bt.z;
  o.w = (z.w - mu) * rstd * gm.w + bt.w;
  *reinterpret_cast<float4*>(out + (size_t)(s * B_ + b) * D_ + (tid << 2)) = o;
}

extern "C" void kernel_launch(void* const* d_in, const int* in_sizes, int n_in,
                              void* d_out, int out_size, void* d_ws, size_t ws_size,
                              hipStream_t stream) {
  const float* q = (const float*)d_in[0];
  const float* k = (const float*)d_in[1];
  const float* v = (const float*)d_in[2];
  const float* sph = (const float*)d_in[3];
  const float* Wq = (const float*)d_in[4];
  const float* Wk = (const float*)d_in[5];
  const float* Wv = (const float*)d_in[6];
  const float* Wo = (const float*)d_in[7];
  const float* gamma = (const float*)d_in[8];
  const float* beta = (const float*)d_in[9];

  float* out = (float*)d_out;                 // [S,B,D]
  float* P = out + (size_t)4 * 1024 * 1024;   // [B,H,S,S]

  char* ws = (char*)d_ws;
  __hip_bfloat16* xq = (__hip_bfloat16*)(ws);                        // 8MB [S*B][D]
  __hip_bfloat16* xk = (__hip_bfloat16*)(ws + ((size_t)8 << 20));    // 8MB
  __hip_bfloat16* xv = (__hip_bfloat16*)(ws + ((size_t)16 << 20));   // 8MB
  __hip_bfloat16* wqb = (__hip_bfloat16*)(ws + ((size_t)24 << 20));  // 2MB
  __hip_bfloat16* wkb = (__hip_bfloat16*)(ws + ((size_t)26 << 20));
  __hip_bfloat16* wvb = (__hip_bfloat16*)(ws + ((size_t)28 << 20));
  __hip_bfloat16* wob = (__hip_bfloat16*)(ws + ((size_t)30 << 20));
  __hip_bfloat16* Qh = (__hip_bfloat16*)(ws + ((size_t)32 << 20));   // 8MB [bh][s][dk]
  __hip_bfloat16* Khb = (__hip_bfloat16*)(ws + ((size_t)40 << 20));  // 8MB [bh][s][dk]
  __hip_bfloat16* VTb = (__hip_bfloat16*)(ws + ((size_t)48 << 20));  // 8MB [bh][dk][s]
  __hip_bfloat16* Ob = (__hip_bfloat16*)(ws + ((size_t)56 << 20));   // 8MB [B][S][D]
  float* Z = (float*)(ws + ((size_t)64 << 20));                      // 16MB [B][S][D]

  const dim3 blk(256);
  k_cvt3<<<12288, blk, 0, stream>>>(q, k, v, xq, xk, xv);
  k_cvt4<<<4096, blk, 0, stream>>>(Wq, Wk, Wv, Wo, wqb, wkb, wvb, wob);

  k_gemm<0><<<dim3(32, 16), blk, 0, stream>>>(xq, wqb, nullptr, Qh, nullptr);
  k_gemm<0><<<dim3(32, 16), blk, 0, stream>>>(xk, wkb, nullptr, Khb, nullptr);
  k_gemm<1><<<dim3(32, 16), blk, 0, stream>>>(xv, wvb, nullptr, VTb, nullptr);

  k_attn<<<dim3(64, 64), blk, 0, stream>>>(Qh, Khb, VTb, sph, P, Ob);

  k_gemm<2><<<dim3(32, 16), blk, 0, stream>>>(Ob, wob, q, nullptr, Z);
  k_ln<<<4096, blk, 0, stream>>>(Z, gamma, beta, out);
}

// Round 6
// 300.414 us; speedup vs baseline: 1.1410x; 1.1410x over previous
//
#include <hip/hip_runtime.h>
#include <hip/hip_bf16.h>
#include <hip/hip_fp16.h>
#include <cstdint>

// Dims
constexpr int B_ = 4, H_ = 16, S_ = 1024, D_ = 1024, DK_ = 64;

typedef __bf16 bf16x8 __attribute__((ext_vector_type(8)));
typedef float f32x4 __attribute__((ext_vector_type(4)));
#define MFMA16(a, b, c) __builtin_amdgcn_mfma_f32_16x16x32_bf16(a, b, c, 0, 0, 0)

static __device__ inline unsigned short f2bf(float f) {
  __hip_bfloat16 h = __float2bfloat16(f);
  return *reinterpret_cast<unsigned short*>(&h);
}
static __device__ inline unsigned packbf(float lo, float hi) {
  return ((unsigned)f2bf(hi) << 16) | (unsigned)f2bf(lo);
}
static __device__ inline unsigned pack_f16(float x, float y) {
  __half hx = __float2half(x), hy = __float2half(y);
  return ((unsigned)(*reinterpret_cast<unsigned short*>(&hy)) << 16) |
         (unsigned)(*reinterpret_cast<unsigned short*>(&hx));
}
static __device__ inline float f16lo(unsigned u) {
  unsigned short s = (unsigned short)(u & 0xffff);
  return __half2float(*reinterpret_cast<__half*>(&s));
}
static __device__ inline float f16hi(unsigned u) {
  unsigned short s = (unsigned short)(u >> 16);
  return __half2float(*reinterpret_cast<__half*>(&s));
}

// ---------------------------------------------------------------------------
// f32 -> bf16 conversions, fused launches
// ---------------------------------------------------------------------------
__global__ __launch_bounds__(256) void k_cvt3(const float* __restrict__ x0,
                                              const float* __restrict__ x1,
                                              const float* __restrict__ x2,
                                              __hip_bfloat16* __restrict__ y0,
                                              __hip_bfloat16* __restrict__ y1,
                                              __hip_bfloat16* __restrict__ y2) {
  const int sel = blockIdx.x >> 12;                       // 4096 blocks per tensor
  const int i = (blockIdx.x & 4095) * 256 + threadIdx.x;  // float4 index
  const float* x = sel == 0 ? x0 : (sel == 1 ? x1 : x2);
  __hip_bfloat16* y = sel == 0 ? y0 : (sel == 1 ? y1 : y2);
  const float4 v = reinterpret_cast<const float4*>(x)[i];
  ushort4 o;
  o.x = f2bf(v.x); o.y = f2bf(v.y); o.z = f2bf(v.z); o.w = f2bf(v.w);
  *reinterpret_cast<ushort4*>(&y[(size_t)i * 4]) = o;
}

__global__ __launch_bounds__(256) void k_cvt4(const float* __restrict__ x0,
                                              const float* __restrict__ x1,
                                              const float* __restrict__ x2,
                                              const float* __restrict__ x3,
                                              __hip_bfloat16* __restrict__ y0,
                                              __hip_bfloat16* __restrict__ y1,
                                              __hip_bfloat16* __restrict__ y2,
                                              __hip_bfloat16* __restrict__ y3) {
  const int sel = blockIdx.x >> 10;                       // 1024 blocks per tensor
  const int i = (blockIdx.x & 1023) * 256 + threadIdx.x;  // float4 index
  const float* x = sel == 0 ? x0 : (sel == 1 ? x1 : (sel == 2 ? x2 : x3));
  __hip_bfloat16* y = sel == 0 ? y0 : (sel == 1 ? y1 : (sel == 2 ? y2 : y3));
  const float4 v = reinterpret_cast<const float4*>(x)[i];
  ushort4 o;
  o.x = f2bf(v.x); o.y = f2bf(v.y); o.z = f2bf(v.z); o.w = f2bf(v.w);
  *reinterpret_cast<ushort4*>(&y[(size_t)i * 4]) = o;
}

// ---------------------------------------------------------------------------
// bf16 MFMA GEMM: C[m,t_tile] = A[m,:] . Bw[t,:]  (A 4096x1024, Bw 1024x1024)
// BM=128, BN=64, BK=64, 256 threads (4 waves, 2x2), per wave 64x32 output.
// LDS chunk-XOR swizzle (16B chunks, chunk^=(row&7)); staged via
// global_load_lds width-16 with pre-swizzled GLOBAL source (linear LDS dest).
// MODE 0: Y bf16 [bh][s][dk], rows m = s*B+b, head = ct
// MODE 1: Y bf16 [bh][dk][s] (transposed; for V)
// MODE 2: Y f32 Z[m][o] = acc + resid[s*B+b][o], rows m = b*S+s
// ---------------------------------------------------------------------------
template <int MODE>
__global__ __launch_bounds__(256) void k_gemm(const __hip_bfloat16* __restrict__ A,
                                              const __hip_bfloat16* __restrict__ Bw,
                                              const float* __restrict__ resid,
                                              __hip_bfloat16* __restrict__ Yb,
                                              float* __restrict__ Yf) {
  __shared__ __hip_bfloat16 Als[128 * 64];
  __shared__ __hip_bfloat16 Bls[64 * 64];
  const int tid = threadIdx.x;
  const int lane = tid & 63;
  const int l15 = lane & 15, g = lane >> 4;
  const int w = tid >> 6;
  const int wr = w >> 1, wc = w & 1;
  const int rt = blockIdx.x, ct = blockIdx.y;
  f32x4 acc[4][2] = {};

  for (int k0 = 0; k0 < D_; k0 += 64) {
    // A: 128 rows x 8 chunks(16B); lds slot s holds global chunk (s&7)^(r&7)
#pragma unroll
    for (int q = 0; q < 4; ++q) {
      const int slot0 = q * 256 + (tid & 192);  // wave-uniform base slot
      const int slot = slot0 + lane;
      const int r = slot >> 3, p = slot & 7;
      const int lc = p ^ (r & 7);
      const __hip_bfloat16* src = A + (size_t)(rt * 128 + r) * D_ + k0 + lc * 8;
      __builtin_amdgcn_global_load_lds(
          (const __attribute__((address_space(1))) unsigned int*)src,
          (__attribute__((address_space(3))) unsigned int*)&Als[slot0 * 8], 16, 0, 0);
    }
#pragma unroll
    for (int q = 0; q < 2; ++q) {
      const int slot0 = q * 256 + (tid & 192);
      const int slot = slot0 + lane;
      const int r = slot >> 3, p = slot & 7;
      const int lc = p ^ (r & 7);
      const __hip_bfloat16* src = Bw + (size_t)(ct * 64 + r) * D_ + k0 + lc * 8;
      __builtin_amdgcn_global_load_lds(
          (const __attribute__((address_space(1))) unsigned int*)src,
          (__attribute__((address_space(3))) unsigned int*)&Bls[slot0 * 8], 16, 0, 0);
    }
    __syncthreads();
#pragma unroll
    for (int ks = 0; ks < 2; ++ks) {
      bf16x8 bfr[2];
#pragma unroll
      for (int cf = 0; cf < 2; ++cf) {
        const int r = wc * 32 + cf * 16 + l15;
        const int p = (ks * 4 + g) ^ (r & 7);
        bfr[cf] = *reinterpret_cast<const bf16x8*>(&Bls[(r * 8 + p) * 8]);
      }
#pragma unroll
      for (int fi = 0; fi < 4; ++fi) {
        const int r = wr * 64 + fi * 16 + l15;
        const int p = (ks * 4 + g) ^ (r & 7);
        const bf16x8 af = *reinterpret_cast<const bf16x8*>(&Als[(r * 8 + p) * 8]);
        acc[fi][0] = MFMA16(af, bfr[0], acc[fi][0]);
        acc[fi][1] = MFMA16(af, bfr[1], acc[fi][1]);
      }
    }
    __syncthreads();
  }
  // epilogue: D-frag col=l15 (B row t), row=4g+reg (A row m)
#pragma unroll
  for (int fi = 0; fi < 4; ++fi)
#pragma unroll
    for (int cf = 0; cf < 2; ++cf)
#pragma unroll
      for (int r = 0; r < 4; ++r) {
        const int m = rt * 128 + wr * 64 + fi * 16 + 4 * g + r;
        const int t = wc * 32 + cf * 16 + l15;
        const float val = acc[fi][cf][r];
        if (MODE == 0) {
          const int s = m >> 2, b = m & 3;
          Yb[((size_t)((b * H_ + ct) * S_ + s)) * DK_ + t] = __float2bfloat16(val);
        } else if (MODE == 1) {
          const int s = m >> 2, b = m & 3;
          Yb[((size_t)((b * H_ + ct) * DK_ + t)) * S_ + s] = __float2bfloat16(val);
        } else {
          const int b = m >> 10, s = m & 1023;
          const int o = ct * 64 + t;
          Yf[(size_t)m * D_ + o] = val + resid[(size_t)(s * B_ + b) * D_ + o];
        }
      }
}

// ---------------------------------------------------------------------------
// Fused attention: per block = 16 query rows of one (b,h). 3 phases:
// P1 (QK^T): wave w owns keys w*256..+255; mfma(K,Q) swapped; RAW qk/8 logits
//    f16-packed to LDS [16][512] u32 pairs (row-XOR swizzle). No sph here.
// P2 (row streaming): wave w owns rows w*4..+3. Per row: LDS logits
//    (lane+64i, conflict-free) + sph row COALESCED (float2/lane, 512B segs)
//    -> modulate -> in-wave softmax -> P row write COALESCED (512B segs)
//    + bf16 repack to LDS.
// P3 (PV): wave w owns outdims w*16..+15; O = mfma(P, V^T-frags).
// ---------------------------------------------------------------------------
__global__ __launch_bounds__(256) void k_attn(const __hip_bfloat16* __restrict__ Qh,
                                              const __hip_bfloat16* __restrict__ Kh,
                                              const __hip_bfloat16* __restrict__ VT,
                                              const float* __restrict__ sph,
                                              float* __restrict__ Pout,
                                              __hip_bfloat16* __restrict__ O) {
  __shared__ unsigned int Plds[16 * 512];  // 32KB
  const int tid = threadIdx.x, lane = tid & 63, w = tid >> 6;
  const int l15 = lane & 15, g = lane >> 4;
  const int it = blockIdx.x, bh = blockIdx.y;
  const unsigned sw = (unsigned)((l15 & 7) << 2);

  // ---- phase 1: raw logits (wave w: keys w*256..+255, queries it*16..+15) --
  {
    const __hip_bfloat16* qp = Qh + ((size_t)bh * S_ + it * 16 + l15) * DK_ + 8 * g;
    const bf16x8 qf0 = *reinterpret_cast<const bf16x8*>(qp);
    const bf16x8 qf1 = *reinterpret_cast<const bf16x8*>(qp + 32);
#pragma unroll
    for (int j = 0; j < 8; ++j) {
      const int key0 = w * 256 + j * 32;
      const __hip_bfloat16* kp = Kh + ((size_t)bh * S_ + key0 + l15) * DK_ + 8 * g;
      const bf16x8 kf0a = *reinterpret_cast<const bf16x8*>(kp);
      const bf16x8 kf0b = *reinterpret_cast<const bf16x8*>(kp + 32);
      const bf16x8 kf1a = *reinterpret_cast<const bf16x8*>(kp + 16 * DK_);
      const bf16x8 kf1b = *reinterpret_cast<const bf16x8*>(kp + 16 * DK_ + 32);
      f32x4 a0 = {0.f, 0.f, 0.f, 0.f};
      f32x4 a1 = {0.f, 0.f, 0.f, 0.f};
      __builtin_amdgcn_s_setprio(1);
      a0 = MFMA16(kf0a, qf0, a0);
      a0 = MFMA16(kf0b, qf1, a0);
      a1 = MFMA16(kf1a, qf0, a1);
      a1 = MFMA16(kf1b, qf1, a1);
      __builtin_amdgcn_s_setprio(0);
      uint2 u0, u1;
      u0.x = pack_f16(a0[0] * 0.125f, a0[1] * 0.125f);
      u0.y = pack_f16(a0[2] * 0.125f, a0[3] * 0.125f);
      u1.x = pack_f16(a1[0] * 0.125f, a1[1] * 0.125f);
      u1.y = pack_f16(a1[2] * 0.125f, a1[3] * 0.125f);
      const int base0 = l15 * 512 + (key0 >> 1) + 2 * g;  // pair index
      *reinterpret_cast<uint2*>(&Plds[(unsigned)base0 ^ sw]) = u0;
      *reinterpret_cast<uint2*>(&Plds[(unsigned)(base0 + 8) ^ sw]) = u1;
    }
  }
  __syncthreads();

  // ---- phase 2: per-row modulate + softmax + coalesced sph/P streams ----
  for (int rr = 0; rr < 4; ++rr) {
    const int row = w * 4 + rr;
    const unsigned rsw = (unsigned)((row & 7) << 2);
    const int lbase = row * 512;
    // LDS raw logits: pairs lane+64i (conflict-free; XOR keeps bank perm)
    unsigned uv[8];
#pragma unroll
    for (int i = 0; i < 8; ++i)
      uv[i] = Plds[(unsigned)(lbase + lane + 64 * i) ^ rsw];
    // sph row, coalesced: lane reads float2 at pair position lane+64i
    const float2* srow = reinterpret_cast<const float2*>(
        sph + ((size_t)bh << 20) + (((size_t)(it * 16 + row)) << 10));
    float2 sv[8];
#pragma unroll
    for (int i = 0; i < 8; ++i) sv[i] = srow[lane + 64 * i];
    float va[16];
#pragma unroll
    for (int i = 0; i < 8; ++i) {
      va[2 * i] = f16lo(uv[i]) * sv[i].x;
      va[2 * i + 1] = f16hi(uv[i]) * sv[i].y;
    }
    float m = va[0];
#pragma unroll
    for (int i = 1; i < 16; ++i) m = fmaxf(m, va[i]);
#pragma unroll
    for (int off = 1; off < 64; off <<= 1) m = fmaxf(m, __shfl_xor(m, off));
    float sum = 0.f;
#pragma unroll
    for (int i = 0; i < 16; ++i) {
      va[i] = __expf(va[i] - m);
      sum += va[i];
    }
#pragma unroll
    for (int off = 1; off < 64; off <<= 1) sum += __shfl_xor(sum, off);
    const float inv = 1.f / sum;
    float2* po = reinterpret_cast<float2*>(Pout + ((size_t)bh << 20) +
                                           (((size_t)(it * 16 + row)) << 10));
#pragma unroll
    for (int i = 0; i < 8; ++i) {
      const float p0 = va[2 * i] * inv, p1 = va[2 * i + 1] * inv;
      po[lane + 64 * i] = make_float2(p0, p1);
      Plds[(unsigned)(lbase + lane + 64 * i) ^ rsw] = packbf(p0, p1);
    }
  }
  __syncthreads();

  // ---- phase 3: PV (wave w: outdims w*16 .. w*16+15) ----
  {
    const int c0 = w * 16;
    f32x4 o0 = {0.f, 0.f, 0.f, 0.f};
    const __hip_bfloat16* vb =
        VT + (size_t)bh * DK_ * S_ + (size_t)(c0 + l15) * S_ + 8 * g;
#pragma unroll 8
    for (int k0 = 0; k0 < S_; k0 += 32) {
      const bf16x8 pa = *reinterpret_cast<const bf16x8*>(
          &Plds[(unsigned)(l15 * 512 + (k0 >> 1) + 4 * g) ^ sw]);
      const bf16x8 vb0 = *reinterpret_cast<const bf16x8*>(vb + k0);
      __builtin_amdgcn_s_setprio(1);
      o0 = MFMA16(pa, vb0, o0);
      __builtin_amdgcn_s_setprio(0);
    }
    const int b = bh >> 4, h = bh & 15;
#pragma unroll
    for (int r = 0; r < 4; ++r) {
      const int srow = it * 16 + 4 * g + r;
      O[((size_t)(b * S_ + srow)) * D_ + h * DK_ + c0 + l15] = __float2bfloat16(o0[r]);
    }
  }
}

// ---------------------------------------------------------------------------
// LayerNorm over D, write [S,B,D]
// ---------------------------------------------------------------------------
__global__ __launch_bounds__(256) void k_ln(const float* __restrict__ Z,
                                            const float* __restrict__ gamma,
                                            const float* __restrict__ beta,
                                            float* __restrict__ out) {
  const int r = blockIdx.x;  // b*S+s
  const int b = r >> 10, s = r & 1023;
  const int tid = threadIdx.x;
  const float4 z = *reinterpret_cast<const float4*>(Z + (size_t)r * D_ + (tid << 2));
  float sum = z.x + z.y + z.z + z.w;
  float sq = z.x * z.x + z.y * z.y + z.z * z.z + z.w * z.w;
#pragma unroll
  for (int off = 1; off < 64; off <<= 1) {
    sum += __shfl_xor(sum, off);
    sq += __shfl_xor(sq, off);
  }
  __shared__ float rs[4];
  __shared__ float rq[4];
  const int wv = tid >> 6, ln = tid & 63;
  if (ln == 0) { rs[wv] = sum; rq[wv] = sq; }
  __syncthreads();
  const float tsum = rs[0] + rs[1] + rs[2] + rs[3];
  const float tsq = rq[0] + rq[1] + rq[2] + rq[3];
  const float mu = tsum * (1.0f / 1024.0f);
  const float var = tsq * (1.0f / 1024.0f) - mu * mu;
  const float rstd = rsqrtf(var + 1e-6f);
  const float4 gm = *reinterpret_cast<const float4*>(gamma + (tid << 2));
  const float4 bt = *reinterpret_cast<const float4*>(beta + (tid << 2));
  float4 o;
  o.x = (z.x - mu) * rstd * gm.x + bt.x;
  o.y = (z.y - mu) * rstd * gm.y + bt.y;
  o.z = (z.z - mu) * rstd * gm.z + bt.z;
  o.w = (z.w - mu) * rstd * gm.w + bt.w;
  *reinterpret_cast<float4*>(out + (size_t)(s * B_ + b) * D_ + (tid << 2)) = o;
}

extern "C" void kernel_launch(void* const* d_in, const int* in_sizes, int n_in,
                              void* d_out, int out_size, void* d_ws, size_t ws_size,
                              hipStream_t stream) {
  const float* q = (const float*)d_in[0];
  const float* k = (const float*)d_in[1];
  const float* v = (const float*)d_in[2];
  const float* sph = (const float*)d_in[3];
  const float* Wq = (const float*)d_in[4];
  const float* Wk = (const float*)d_in[5];
  const float* Wv = (const float*)d_in[6];
  const float* Wo = (const float*)d_in[7];
  const float* gamma = (const float*)d_in[8];
  const float* beta = (const float*)d_in[9];

  float* out = (float*)d_out;                 // [S,B,D]
  float* P = out + (size_t)4 * 1024 * 1024;   // [B,H,S,S]

  char* ws = (char*)d_ws;
  __hip_bfloat16* xq = (__hip_bfloat16*)(ws);                        // 8MB [S*B][D]
  __hip_bfloat16* xk = (__hip_bfloat16*)(ws + ((size_t)8 << 20));    // 8MB
  __hip_bfloat16* xv = (__hip_bfloat16*)(ws + ((size_t)16 << 20));   // 8MB
  __hip_bfloat16* wqb = (__hip_bfloat16*)(ws + ((size_t)24 << 20));  // 2MB
  __hip_bfloat16* wkb = (__hip_bfloat16*)(ws + ((size_t)26 << 20));
  __hip_bfloat16* wvb = (__hip_bfloat16*)(ws + ((size_t)28 << 20));
  __hip_bfloat16* wob = (__hip_bfloat16*)(ws + ((size_t)30 << 20));
  __hip_bfloat16* Qh = (__hip_bfloat16*)(ws + ((size_t)32 << 20));   // 8MB [bh][s][dk]
  __hip_bfloat16* Khb = (__hip_bfloat16*)(ws + ((size_t)40 << 20));  // 8MB [bh][s][dk]
  __hip_bfloat16* VTb = (__hip_bfloat16*)(ws + ((size_t)48 << 20));  // 8MB [bh][dk][s]
  __hip_bfloat16* Ob = (__hip_bfloat16*)(ws + ((size_t)56 << 20));   // 8MB [B][S][D]
  float* Z = (float*)(ws + ((size_t)64 << 20));                      // 16MB [B][S][D]

  const dim3 blk(256);
  k_cvt3<<<12288, blk, 0, stream>>>(q, k, v, xq, xk, xv);
  k_cvt4<<<4096, blk, 0, stream>>>(Wq, Wk, Wv, Wo, wqb, wkb, wvb, wob);

  k_gemm<0><<<dim3(32, 16), blk, 0, stream>>>(xq, wqb, nullptr, Qh, nullptr);
  k_gemm<0><<<dim3(32, 16), blk, 0, stream>>>(xk, wkb, nullptr, Khb, nullptr);
  k_gemm<1><<<dim3(32, 16), blk, 0, stream>>>(xv, wvb, nullptr, VTb, nullptr);

  k_attn<<<dim3(64, 64), blk, 0, stream>>>(Qh, Khb, VTb, sph, P, Ob);

  k_gemm<2><<<dim3(32, 16), blk, 0, stream>>>(Ob, wob, q, nullptr, Z);
  k_ln<<<4096, blk, 0, stream>>>(Z, gamma, beta, out);
}

// Round 7
// 288.752 us; speedup vs baseline: 1.1870x; 1.0404x over previous
//
#include <hip/hip_runtime.h>
#include <hip/hip_bf16.h>
#include <hip/hip_fp16.h>
#include <cstdint>

// Dims
constexpr int B_ = 4, H_ = 16, S_ = 1024, D_ = 1024, DK_ = 64;

typedef __bf16 bf16x8 __attribute__((ext_vector_type(8)));
typedef float f32x4 __attribute__((ext_vector_type(4)));
#define MFMA16(a, b, c) __builtin_amdgcn_mfma_f32_16x16x32_bf16(a, b, c, 0, 0, 0)

static __device__ inline unsigned short f2bf(float f) {
  __hip_bfloat16 h = __float2bfloat16(f);
  return *reinterpret_cast<unsigned short*>(&h);
}
static __device__ inline unsigned packbf(float lo, float hi) {
  return ((unsigned)f2bf(hi) << 16) | (unsigned)f2bf(lo);
}
static __device__ inline unsigned pack_f16(float x, float y) {
  __half hx = __float2half(x), hy = __float2half(y);
  return ((unsigned)(*reinterpret_cast<unsigned short*>(&hy)) << 16) |
         (unsigned)(*reinterpret_cast<unsigned short*>(&hx));
}
static __device__ inline float f16lo(unsigned u) {
  unsigned short s = (unsigned short)(u & 0xffff);
  return __half2float(*reinterpret_cast<__half*>(&s));
}
static __device__ inline float f16hi(unsigned u) {
  unsigned short s = (unsigned short)(u >> 16);
  return __half2float(*reinterpret_cast<__half*>(&s));
}

// ---------------------------------------------------------------------------
// f32 -> bf16 conversions, fused launches
// ---------------------------------------------------------------------------
__global__ __launch_bounds__(256) void k_cvt3(const float* __restrict__ x0,
                                              const float* __restrict__ x1,
                                              const float* __restrict__ x2,
                                              __hip_bfloat16* __restrict__ y0,
                                              __hip_bfloat16* __restrict__ y1,
                                              __hip_bfloat16* __restrict__ y2) {
  const int sel = blockIdx.x >> 12;                       // 4096 blocks per tensor
  const int i = (blockIdx.x & 4095) * 256 + threadIdx.x;  // float4 index
  const float* x = sel == 0 ? x0 : (sel == 1 ? x1 : x2);
  __hip_bfloat16* y = sel == 0 ? y0 : (sel == 1 ? y1 : y2);
  const float4 v = reinterpret_cast<const float4*>(x)[i];
  ushort4 o;
  o.x = f2bf(v.x); o.y = f2bf(v.y); o.z = f2bf(v.z); o.w = f2bf(v.w);
  *reinterpret_cast<ushort4*>(&y[(size_t)i * 4]) = o;
}

__global__ __launch_bounds__(256) void k_cvt4(const float* __restrict__ x0,
                                              const float* __restrict__ x1,
                                              const float* __restrict__ x2,
                                              const float* __restrict__ x3,
                                              __hip_bfloat16* __restrict__ y0,
                                              __hip_bfloat16* __restrict__ y1,
                                              __hip_bfloat16* __restrict__ y2,
                                              __hip_bfloat16* __restrict__ y3) {
  const int sel = blockIdx.x >> 10;                       // 1024 blocks per tensor
  const int i = (blockIdx.x & 1023) * 256 + threadIdx.x;  // float4 index
  const float* x = sel == 0 ? x0 : (sel == 1 ? x1 : (sel == 2 ? x2 : x3));
  __hip_bfloat16* y = sel == 0 ? y0 : (sel == 1 ? y1 : (sel == 2 ? y2 : y3));
  const float4 v = reinterpret_cast<const float4*>(x)[i];
  ushort4 o;
  o.x = f2bf(v.x); o.y = f2bf(v.y); o.z = f2bf(v.z); o.w = f2bf(v.w);
  *reinterpret_cast<ushort4*>(&y[(size_t)i * 4]) = o;
}

// ---------------------------------------------------------------------------
// bf16 MFMA GEMM (unchanged from round 6)
// ---------------------------------------------------------------------------
template <int MODE>
__global__ __launch_bounds__(256) void k_gemm(const __hip_bfloat16* __restrict__ A,
                                              const __hip_bfloat16* __restrict__ Bw,
                                              const float* __restrict__ resid,
                                              __hip_bfloat16* __restrict__ Yb,
                                              float* __restrict__ Yf) {
  __shared__ __hip_bfloat16 Als[128 * 64];
  __shared__ __hip_bfloat16 Bls[64 * 64];
  const int tid = threadIdx.x;
  const int lane = tid & 63;
  const int l15 = lane & 15, g = lane >> 4;
  const int w = tid >> 6;
  const int wr = w >> 1, wc = w & 1;
  const int rt = blockIdx.x, ct = blockIdx.y;
  f32x4 acc[4][2] = {};

  for (int k0 = 0; k0 < D_; k0 += 64) {
#pragma unroll
    for (int q = 0; q < 4; ++q) {
      const int slot0 = q * 256 + (tid & 192);
      const int slot = slot0 + lane;
      const int r = slot >> 3, p = slot & 7;
      const int lc = p ^ (r & 7);
      const __hip_bfloat16* src = A + (size_t)(rt * 128 + r) * D_ + k0 + lc * 8;
      __builtin_amdgcn_global_load_lds(
          (const __attribute__((address_space(1))) unsigned int*)src,
          (__attribute__((address_space(3))) unsigned int*)&Als[slot0 * 8], 16, 0, 0);
    }
#pragma unroll
    for (int q = 0; q < 2; ++q) {
      const int slot0 = q * 256 + (tid & 192);
      const int slot = slot0 + lane;
      const int r = slot >> 3, p = slot & 7;
      const int lc = p ^ (r & 7);
      const __hip_bfloat16* src = Bw + (size_t)(ct * 64 + r) * D_ + k0 + lc * 8;
      __builtin_amdgcn_global_load_lds(
          (const __attribute__((address_space(1))) unsigned int*)src,
          (__attribute__((address_space(3))) unsigned int*)&Bls[slot0 * 8], 16, 0, 0);
    }
    __syncthreads();
#pragma unroll
    for (int ks = 0; ks < 2; ++ks) {
      bf16x8 bfr[2];
#pragma unroll
      for (int cf = 0; cf < 2; ++cf) {
        const int r = wc * 32 + cf * 16 + l15;
        const int p = (ks * 4 + g) ^ (r & 7);
        bfr[cf] = *reinterpret_cast<const bf16x8*>(&Bls[(r * 8 + p) * 8]);
      }
#pragma unroll
      for (int fi = 0; fi < 4; ++fi) {
        const int r = wr * 64 + fi * 16 + l15;
        const int p = (ks * 4 + g) ^ (r & 7);
        const bf16x8 af = *reinterpret_cast<const bf16x8*>(&Als[(r * 8 + p) * 8]);
        acc[fi][0] = MFMA16(af, bfr[0], acc[fi][0]);
        acc[fi][1] = MFMA16(af, bfr[1], acc[fi][1]);
      }
    }
    __syncthreads();
  }
#pragma unroll
  for (int fi = 0; fi < 4; ++fi)
#pragma unroll
    for (int cf = 0; cf < 2; ++cf)
#pragma unroll
      for (int r = 0; r < 4; ++r) {
        const int m = rt * 128 + wr * 64 + fi * 16 + 4 * g + r;
        const int t = wc * 32 + cf * 16 + l15;
        const float val = acc[fi][cf][r];
        if (MODE == 0) {
          const int s = m >> 2, b = m & 3;
          Yb[((size_t)((b * H_ + ct) * S_ + s)) * DK_ + t] = __float2bfloat16(val);
        } else if (MODE == 1) {
          const int s = m >> 2, b = m & 3;
          Yb[((size_t)((b * H_ + ct) * DK_ + t)) * S_ + s] = __float2bfloat16(val);
        } else {
          const int b = m >> 10, s = m & 1023;
          const int o = ct * 64 + t;
          Yf[(size_t)m * D_ + o] = val + resid[(size_t)(s * B_ + b) * D_ + o];
        }
      }
}

// ---------------------------------------------------------------------------
// Fused attention, MLP-deepened:
// P1: 2-deep K-fragment pipeline (j+1 loads in flight during j's MFMA+pack).
// P2: 2-deep row pipeline (row rr+1 sph loads issued before row rr reduce).
// P3: batches of 8 (8 VT loads + 8 LDS reads + 8 MFMA).
// Same math/addresses as round 6 (passed, absmax 0.03125).
// ---------------------------------------------------------------------------
__global__ __launch_bounds__(256) void k_attn(const __hip_bfloat16* __restrict__ Qh,
                                              const __hip_bfloat16* __restrict__ Kh,
                                              const __hip_bfloat16* __restrict__ VT,
                                              const float* __restrict__ sph,
                                              float* __restrict__ Pout,
                                              __hip_bfloat16* __restrict__ O) {
  __shared__ unsigned int Plds[16 * 512];  // 32KB
  const int tid = threadIdx.x, lane = tid & 63, w = tid >> 6;
  const int l15 = lane & 15, g = lane >> 4;
  const int it = blockIdx.x, bh = blockIdx.y;
  const unsigned sw = (unsigned)((l15 & 7) << 2);

  // ---- phase 1: raw logits; 2-deep K pipeline ----
  {
    const __hip_bfloat16* qp = Qh + ((size_t)bh * S_ + it * 16 + l15) * DK_ + 8 * g;
    const bf16x8 qf0 = *reinterpret_cast<const bf16x8*>(qp);
    const bf16x8 qf1 = *reinterpret_cast<const bf16x8*>(qp + 32);
    const __hip_bfloat16* kb0 =
        Kh + (size_t)bh * S_ * DK_ + (size_t)(w * 256 + l15) * DK_ + 8 * g;
    bf16x8 kra[2], krb[2], krc[2], krd[2];
    kra[0] = *reinterpret_cast<const bf16x8*>(kb0);
    krb[0] = *reinterpret_cast<const bf16x8*>(kb0 + 32);
    krc[0] = *reinterpret_cast<const bf16x8*>(kb0 + 16 * DK_);
    krd[0] = *reinterpret_cast<const bf16x8*>(kb0 + 16 * DK_ + 32);
#pragma unroll
    for (int j = 0; j < 8; ++j) {
      const int cur = j & 1, nxt = cur ^ 1;
      if (j < 7) {
        const __hip_bfloat16* kp = kb0 + (size_t)(j + 1) * 32 * DK_;
        kra[nxt] = *reinterpret_cast<const bf16x8*>(kp);
        krb[nxt] = *reinterpret_cast<const bf16x8*>(kp + 32);
        krc[nxt] = *reinterpret_cast<const bf16x8*>(kp + 16 * DK_);
        krd[nxt] = *reinterpret_cast<const bf16x8*>(kp + 16 * DK_ + 32);
      }
      f32x4 a0 = {0.f, 0.f, 0.f, 0.f};
      f32x4 a1 = {0.f, 0.f, 0.f, 0.f};
      __builtin_amdgcn_s_setprio(1);
      a0 = MFMA16(kra[cur], qf0, a0);
      a0 = MFMA16(krb[cur], qf1, a0);
      a1 = MFMA16(krc[cur], qf0, a1);
      a1 = MFMA16(krd[cur], qf1, a1);
      __builtin_amdgcn_s_setprio(0);
      const int key0 = w * 256 + j * 32;
      uint2 u0, u1;
      u0.x = pack_f16(a0[0] * 0.125f, a0[1] * 0.125f);
      u0.y = pack_f16(a0[2] * 0.125f, a0[3] * 0.125f);
      u1.x = pack_f16(a1[0] * 0.125f, a1[1] * 0.125f);
      u1.y = pack_f16(a1[2] * 0.125f, a1[3] * 0.125f);
      const int base0 = l15 * 512 + (key0 >> 1) + 2 * g;  // pair index
      *reinterpret_cast<uint2*>(&Plds[(unsigned)base0 ^ sw]) = u0;
      *reinterpret_cast<uint2*>(&Plds[(unsigned)(base0 + 8) ^ sw]) = u1;
    }
  }
  __syncthreads();

  // ---- phase 2: per-row modulate+softmax; 2-deep row pipeline ----
  {
    const float2* sbase = reinterpret_cast<const float2*>(
        sph + ((size_t)bh << 20) + (((size_t)(it * 16)) << 10));
    float2 svbuf[2][8];
#pragma unroll
    for (int i = 0; i < 8; ++i)
      svbuf[0][i] = sbase[(size_t)(w * 4) * 512 + lane + 64 * i];
#pragma unroll
    for (int rr = 0; rr < 4; ++rr) {
      const int row = w * 4 + rr;
      if (rr < 3) {
#pragma unroll
        for (int i = 0; i < 8; ++i)
          svbuf[(rr + 1) & 1][i] = sbase[(size_t)(row + 1) * 512 + lane + 64 * i];
      }
      const unsigned rsw = (unsigned)((row & 7) << 2);
      const int lbase = row * 512;
      unsigned uv[8];
#pragma unroll
      for (int i = 0; i < 8; ++i)
        uv[i] = Plds[(unsigned)(lbase + lane + 64 * i) ^ rsw];
      float va[16];
#pragma unroll
      for (int i = 0; i < 8; ++i) {
        va[2 * i] = f16lo(uv[i]) * svbuf[rr & 1][i].x;
        va[2 * i + 1] = f16hi(uv[i]) * svbuf[rr & 1][i].y;
      }
      float m = va[0];
#pragma unroll
      for (int i = 1; i < 16; ++i) m = fmaxf(m, va[i]);
#pragma unroll
      for (int off = 1; off < 64; off <<= 1) m = fmaxf(m, __shfl_xor(m, off));
      float sum = 0.f;
#pragma unroll
      for (int i = 0; i < 16; ++i) {
        va[i] = __expf(va[i] - m);
        sum += va[i];
      }
#pragma unroll
      for (int off = 1; off < 64; off <<= 1) sum += __shfl_xor(sum, off);
      const float inv = 1.f / sum;
      float2* po = reinterpret_cast<float2*>(Pout + ((size_t)bh << 20) +
                                             (((size_t)(it * 16 + row)) << 10));
#pragma unroll
      for (int i = 0; i < 8; ++i) {
        const float p0 = va[2 * i] * inv, p1 = va[2 * i + 1] * inv;
        po[lane + 64 * i] = make_float2(p0, p1);
        Plds[(unsigned)(lbase + lane + 64 * i) ^ rsw] = packbf(p0, p1);
      }
    }
  }
  __syncthreads();

  // ---- phase 3: PV, batches of 8 (8 KB in flight) ----
  {
    const int c0 = w * 16;
    f32x4 o0 = {0.f, 0.f, 0.f, 0.f};
    const __hip_bfloat16* vb =
        VT + (size_t)bh * DK_ * S_ + (size_t)(c0 + l15) * S_ + 8 * g;
#pragma unroll
    for (int kb2 = 0; kb2 < 4; ++kb2) {
      bf16x8 vreg[8];
      bf16x8 preg[8];
#pragma unroll
      for (int u = 0; u < 8; ++u)
        vreg[u] = *reinterpret_cast<const bf16x8*>(vb + kb2 * 256 + u * 32);
#pragma unroll
      for (int u = 0; u < 8; ++u) {
        const int k0 = kb2 * 256 + u * 32;
        preg[u] = *reinterpret_cast<const bf16x8*>(
            &Plds[(unsigned)(l15 * 512 + (k0 >> 1) + 4 * g) ^ sw]);
      }
      __builtin_amdgcn_s_setprio(1);
#pragma unroll
      for (int u = 0; u < 8; ++u) o0 = MFMA16(preg[u], vreg[u], o0);
      __builtin_amdgcn_s_setprio(0);
    }
    const int b = bh >> 4, h = bh & 15;
#pragma unroll
    for (int r = 0; r < 4; ++r) {
      const int srow = it * 16 + 4 * g + r;
      O[((size_t)(b * S_ + srow)) * D_ + h * DK_ + c0 + l15] = __float2bfloat16(o0[r]);
    }
  }
}

// ---------------------------------------------------------------------------
// LayerNorm over D, write [S,B,D]
// ---------------------------------------------------------------------------
__global__ __launch_bounds__(256) void k_ln(const float* __restrict__ Z,
                                            const float* __restrict__ gamma,
                                            const float* __restrict__ beta,
                                            float* __restrict__ out) {
  const int r = blockIdx.x;  // b*S+s
  const int b = r >> 10, s = r & 1023;
  const int tid = threadIdx.x;
  const float4 z = *reinterpret_cast<const float4*>(Z + (size_t)r * D_ + (tid << 2));
  float sum = z.x + z.y + z.z + z.w;
  float sq = z.x * z.x + z.y * z.y + z.z * z.z + z.w * z.w;
#pragma unroll
  for (int off = 1; off < 64; off <<= 1) {
    sum += __shfl_xor(sum, off);
    sq += __shfl_xor(sq, off);
  }
  __shared__ float rs[4];
  __shared__ float rq[4];
  const int wv = tid >> 6, ln = tid & 63;
  if (ln == 0) { rs[wv] = sum; rq[wv] = sq; }
  __syncthreads();
  const float tsum = rs[0] + rs[1] + rs[2] + rs[3];
  const float tsq = rq[0] + rq[1] + rq[2] + rq[3];
  const float mu = tsum * (1.0f / 1024.0f);
  const float var = tsq * (1.0f / 1024.0f) - mu * mu;
  const float rstd = rsqrtf(var + 1e-6f);
  const float4 gm = *reinterpret_cast<const float4*>(gamma + (tid << 2));
  const float4 bt = *reinterpret_cast<const float4*>(beta + (tid << 2));
  float4 o;
  o.x = (z.x - mu) * rstd * gm.x + bt.x;
  o.y = (z.y - mu) * rstd * gm.y + bt.y;
  o.z = (z.z - mu) * rstd * gm.z + bt.z;
  o.w = (z.w - mu) * rstd * gm.w + bt.w;
  *reinterpret_cast<float4*>(out + (size_t)(s * B_ + b) * D_ + (tid << 2)) = o;
}

extern "C" void kernel_launch(void* const* d_in, const int* in_sizes, int n_in,
                              void* d_out, int out_size, void* d_ws, size_t ws_size,
                              hipStream_t stream) {
  const float* q = (const float*)d_in[0];
  const float* k = (const float*)d_in[1];
  const float* v = (const float*)d_in[2];
  const float* sph = (const float*)d_in[3];
  const float* Wq = (const float*)d_in[4];
  const float* Wk = (const float*)d_in[5];
  const float* Wv = (const float*)d_in[6];
  const float* Wo = (const float*)d_in[7];
  const float* gamma = (const float*)d_in[8];
  const float* beta = (const float*)d_in[9];

  float* out = (float*)d_out;                 // [S,B,D]
  float* P = out + (size_t)4 * 1024 * 1024;   // [B,H,S,S]

  char* ws = (char*)d_ws;
  __hip_bfloat16* xq = (__hip_bfloat16*)(ws);                        // 8MB [S*B][D]
  __hip_bfloat16* xk = (__hip_bfloat16*)(ws + ((size_t)8 << 20));    // 8MB
  __hip_bfloat16* xv = (__hip_bfloat16*)(ws + ((size_t)16 << 20));   // 8MB
  __hip_bfloat16* wqb = (__hip_bfloat16*)(ws + ((size_t)24 << 20));  // 2MB
  __hip_bfloat16* wkb = (__hip_bfloat16*)(ws + ((size_t)26 << 20));
  __hip_bfloat16* wvb = (__hip_bfloat16*)(ws + ((size_t)28 << 20));
  __hip_bfloat16* wob = (__hip_bfloat16*)(ws + ((size_t)30 << 20));
  __hip_bfloat16* Qh = (__hip_bfloat16*)(ws + ((size_t)32 << 20));   // 8MB [bh][s][dk]
  __hip_bfloat16* Khb = (__hip_bfloat16*)(ws + ((size_t)40 << 20));  // 8MB [bh][s][dk]
  __hip_bfloat16* VTb = (__hip_bfloat16*)(ws + ((size_t)48 << 20));  // 8MB [bh][dk][s]
  __hip_bfloat16* Ob = (__hip_bfloat16*)(ws + ((size_t)56 << 20));   // 8MB [B][S][D]
  float* Z = (float*)(ws + ((size_t)64 << 20));                      // 16MB [B][S][D]

  const dim3 blk(256);
  k_cvt3<<<12288, blk, 0, stream>>>(q, k, v, xq, xk, xv);
  k_cvt4<<<4096, blk, 0, stream>>>(Wq, Wk, Wv, Wo, wqb, wkb, wvb, wob);

  k_gemm<0><<<dim3(32, 16), blk, 0, stream>>>(xq, wqb, nullptr, Qh, nullptr);
  k_gemm<0><<<dim3(32, 16), blk, 0, stream>>>(xk, wkb, nullptr, Khb, nullptr);
  k_gemm<1><<<dim3(32, 16), blk, 0, stream>>>(xv, wvb, nullptr, VTb, nullptr);

  k_attn<<<dim3(64, 64), blk, 0, stream>>>(Qh, Khb, VTb, sph, P, Ob);

  k_gemm<2><<<dim3(32, 16), blk, 0, stream>>>(Ob, wob, q, nullptr, Z);
  k_ln<<<4096, blk, 0, stream>>>(Z, gamma, beta, out);
}

// Round 8
// 286.181 us; speedup vs baseline: 1.1977x; 1.0090x over previous
//
#include <hip/hip_runtime.h>
#include <hip/hip_bf16.h>
#include <hip/hip_fp16.h>
#include <cstdint>

// Dims
constexpr int B_ = 4, H_ = 16, S_ = 1024, D_ = 1024, DK_ = 64;

typedef __bf16 bf16x8 __attribute__((ext_vector_type(8)));
typedef float f32x4 __attribute__((ext_vector_type(4)));
#define MFMA16(a, b, c) __builtin_amdgcn_mfma_f32_16x16x32_bf16(a, b, c, 0, 0, 0)

static __device__ inline unsigned short f2bf(float f) {
  __hip_bfloat16 h = __float2bfloat16(f);
  return *reinterpret_cast<unsigned short*>(&h);
}
static __device__ inline unsigned packbf(float lo, float hi) {
  return ((unsigned)f2bf(hi) << 16) | (unsigned)f2bf(lo);
}
static __device__ inline unsigned pack_f16(float x, float y) {
  __half hx = __float2half(x), hy = __float2half(y);
  return ((unsigned)(*reinterpret_cast<unsigned short*>(&hy)) << 16) |
         (unsigned)(*reinterpret_cast<unsigned short*>(&hx));
}
static __device__ inline float f16lo(unsigned u) {
  unsigned short s = (unsigned short)(u & 0xffff);
  return __half2float(*reinterpret_cast<__half*>(&s));
}
static __device__ inline float f16hi(unsigned u) {
  unsigned short s = (unsigned short)(u >> 16);
  return __half2float(*reinterpret_cast<__half*>(&s));
}

// ---------------------------------------------------------------------------
// f32 -> bf16 conversions, fused launches
// ---------------------------------------------------------------------------
__global__ __launch_bounds__(256) void k_cvt3(const float* __restrict__ x0,
                                              const float* __restrict__ x1,
                                              const float* __restrict__ x2,
                                              __hip_bfloat16* __restrict__ y0,
                                              __hip_bfloat16* __restrict__ y1,
                                              __hip_bfloat16* __restrict__ y2) {
  const int sel = blockIdx.x >> 12;                       // 4096 blocks per tensor
  const int i = (blockIdx.x & 4095) * 256 + threadIdx.x;  // float4 index
  const float* x = sel == 0 ? x0 : (sel == 1 ? x1 : x2);
  __hip_bfloat16* y = sel == 0 ? y0 : (sel == 1 ? y1 : y2);
  const float4 v = reinterpret_cast<const float4*>(x)[i];
  ushort4 o;
  o.x = f2bf(v.x); o.y = f2bf(v.y); o.z = f2bf(v.z); o.w = f2bf(v.w);
  *reinterpret_cast<ushort4*>(&y[(size_t)i * 4]) = o;
}

__global__ __launch_bounds__(256) void k_cvt4(const float* __restrict__ x0,
                                              const float* __restrict__ x1,
                                              const float* __restrict__ x2,
                                              const float* __restrict__ x3,
                                              __hip_bfloat16* __restrict__ y0,
                                              __hip_bfloat16* __restrict__ y1,
                                              __hip_bfloat16* __restrict__ y2,
                                              __hip_bfloat16* __restrict__ y3) {
  const int sel = blockIdx.x >> 10;                       // 1024 blocks per tensor
  const int i = (blockIdx.x & 1023) * 256 + threadIdx.x;  // float4 index
  const float* x = sel == 0 ? x0 : (sel == 1 ? x1 : (sel == 2 ? x2 : x3));
  __hip_bfloat16* y = sel == 0 ? y0 : (sel == 1 ? y1 : (sel == 2 ? y2 : y3));
  const float4 v = reinterpret_cast<const float4*>(x)[i];
  ushort4 o;
  o.x = f2bf(v.x); o.y = f2bf(v.y); o.z = f2bf(v.z); o.w = f2bf(v.w);
  *reinterpret_cast<ushort4*>(&y[(size_t)i * 4]) = o;
}

// ---------------------------------------------------------------------------
// bf16 MFMA GEMM (unchanged)
// ---------------------------------------------------------------------------
template <int MODE>
__global__ __launch_bounds__(256) void k_gemm(const __hip_bfloat16* __restrict__ A,
                                              const __hip_bfloat16* __restrict__ Bw,
                                              const float* __restrict__ resid,
                                              __hip_bfloat16* __restrict__ Yb,
                                              float* __restrict__ Yf) {
  __shared__ __hip_bfloat16 Als[128 * 64];
  __shared__ __hip_bfloat16 Bls[64 * 64];
  const int tid = threadIdx.x;
  const int lane = tid & 63;
  const int l15 = lane & 15, g = lane >> 4;
  const int w = tid >> 6;
  const int wr = w >> 1, wc = w & 1;
  const int rt = blockIdx.x, ct = blockIdx.y;
  f32x4 acc[4][2] = {};

  for (int k0 = 0; k0 < D_; k0 += 64) {
#pragma unroll
    for (int q = 0; q < 4; ++q) {
      const int slot0 = q * 256 + (tid & 192);
      const int slot = slot0 + lane;
      const int r = slot >> 3, p = slot & 7;
      const int lc = p ^ (r & 7);
      const __hip_bfloat16* src = A + (size_t)(rt * 128 + r) * D_ + k0 + lc * 8;
      __builtin_amdgcn_global_load_lds(
          (const __attribute__((address_space(1))) unsigned int*)src,
          (__attribute__((address_space(3))) unsigned int*)&Als[slot0 * 8], 16, 0, 0);
    }
#pragma unroll
    for (int q = 0; q < 2; ++q) {
      const int slot0 = q * 256 + (tid & 192);
      const int slot = slot0 + lane;
      const int r = slot >> 3, p = slot & 7;
      const int lc = p ^ (r & 7);
      const __hip_bfloat16* src = Bw + (size_t)(ct * 64 + r) * D_ + k0 + lc * 8;
      __builtin_amdgcn_global_load_lds(
          (const __attribute__((address_space(1))) unsigned int*)src,
          (__attribute__((address_space(3))) unsigned int*)&Bls[slot0 * 8], 16, 0, 0);
    }
    __syncthreads();
#pragma unroll
    for (int ks = 0; ks < 2; ++ks) {
      bf16x8 bfr[2];
#pragma unroll
      for (int cf = 0; cf < 2; ++cf) {
        const int r = wc * 32 + cf * 16 + l15;
        const int p = (ks * 4 + g) ^ (r & 7);
        bfr[cf] = *reinterpret_cast<const bf16x8*>(&Bls[(r * 8 + p) * 8]);
      }
#pragma unroll
      for (int fi = 0; fi < 4; ++fi) {
        const int r = wr * 64 + fi * 16 + l15;
        const int p = (ks * 4 + g) ^ (r & 7);
        const bf16x8 af = *reinterpret_cast<const bf16x8*>(&Als[(r * 8 + p) * 8]);
        acc[fi][0] = MFMA16(af, bfr[0], acc[fi][0]);
        acc[fi][1] = MFMA16(af, bfr[1], acc[fi][1]);
      }
    }
    __syncthreads();
  }
#pragma unroll
  for (int fi = 0; fi < 4; ++fi)
#pragma unroll
    for (int cf = 0; cf < 2; ++cf)
#pragma unroll
      for (int r = 0; r < 4; ++r) {
        const int m = rt * 128 + wr * 64 + fi * 16 + 4 * g + r;
        const int t = wc * 32 + cf * 16 + l15;
        const float val = acc[fi][cf][r];
        if (MODE == 0) {
          const int s = m >> 2, b = m & 3;
          Yb[((size_t)((b * H_ + ct) * S_ + s)) * DK_ + t] = __float2bfloat16(val);
        } else if (MODE == 1) {
          const int s = m >> 2, b = m & 3;
          Yb[((size_t)((b * H_ + ct) * DK_ + t)) * S_ + s] = __float2bfloat16(val);
        } else {
          const int b = m >> 10, s = m & 1023;
          const int o = ct * 64 + t;
          Yf[(size_t)m * D_ + o] = val + resid[(size_t)(s * B_ + b) * D_ + o];
        }
      }
}

// ---------------------------------------------------------------------------
// Fused attention. __launch_bounds__(256,4): 128-VGPR budget so the software
// pipelines actually stay in registers (R7 post-mortem: at the default
// 8-waves/EU target the allocator serialized all prefetches; LDS already
// caps occupancy at ~5 blocks/CU so the extra VGPRs are free).
// P1: 2-deep K-fragment pipeline; raw qk/8 -> f16 pairs in LDS.
// P2: 2-deep row pipeline; float4 sph loads + float4 P stores (1KB segs).
// P3: batches of 8 (8 VT loads + 8 LDS reads + 8 MFMA).
// ---------------------------------------------------------------------------
__global__ __launch_bounds__(256, 4) void k_attn(const __hip_bfloat16* __restrict__ Qh,
                                                 const __hip_bfloat16* __restrict__ Kh,
                                                 const __hip_bfloat16* __restrict__ VT,
                                                 const float* __restrict__ sph,
                                                 float* __restrict__ Pout,
                                                 __hip_bfloat16* __restrict__ O) {
  __shared__ unsigned int Plds[16 * 512];  // 32KB
  const int tid = threadIdx.x, lane = tid & 63, w = tid >> 6;
  const int l15 = lane & 15, g = lane >> 4;
  const int it = blockIdx.x, bh = blockIdx.y;
  const unsigned sw = (unsigned)((l15 & 7) << 2);

  // ---- phase 1: raw logits; 2-deep K pipeline ----
  {
    const __hip_bfloat16* qp = Qh + ((size_t)bh * S_ + it * 16 + l15) * DK_ + 8 * g;
    const bf16x8 qf0 = *reinterpret_cast<const bf16x8*>(qp);
    const bf16x8 qf1 = *reinterpret_cast<const bf16x8*>(qp + 32);
    const __hip_bfloat16* kb0 =
        Kh + (size_t)bh * S_ * DK_ + (size_t)(w * 256 + l15) * DK_ + 8 * g;
    bf16x8 kra[2], krb[2], krc[2], krd[2];
    kra[0] = *reinterpret_cast<const bf16x8*>(kb0);
    krb[0] = *reinterpret_cast<const bf16x8*>(kb0 + 32);
    krc[0] = *reinterpret_cast<const bf16x8*>(kb0 + 16 * DK_);
    krd[0] = *reinterpret_cast<const bf16x8*>(kb0 + 16 * DK_ + 32);
#pragma unroll
    for (int j = 0; j < 8; ++j) {
      const int cur = j & 1, nxt = cur ^ 1;
      if (j < 7) {
        const __hip_bfloat16* kp = kb0 + (size_t)(j + 1) * 32 * DK_;
        kra[nxt] = *reinterpret_cast<const bf16x8*>(kp);
        krb[nxt] = *reinterpret_cast<const bf16x8*>(kp + 32);
        krc[nxt] = *reinterpret_cast<const bf16x8*>(kp + 16 * DK_);
        krd[nxt] = *reinterpret_cast<const bf16x8*>(kp + 16 * DK_ + 32);
      }
      f32x4 a0 = {0.f, 0.f, 0.f, 0.f};
      f32x4 a1 = {0.f, 0.f, 0.f, 0.f};
      __builtin_amdgcn_s_setprio(1);
      a0 = MFMA16(kra[cur], qf0, a0);
      a0 = MFMA16(krb[cur], qf1, a0);
      a1 = MFMA16(krc[cur], qf0, a1);
      a1 = MFMA16(krd[cur], qf1, a1);
      __builtin_amdgcn_s_setprio(0);
      const int key0 = w * 256 + j * 32;
      uint2 u0, u1;
      u0.x = pack_f16(a0[0] * 0.125f, a0[1] * 0.125f);
      u0.y = pack_f16(a0[2] * 0.125f, a0[3] * 0.125f);
      u1.x = pack_f16(a1[0] * 0.125f, a1[1] * 0.125f);
      u1.y = pack_f16(a1[2] * 0.125f, a1[3] * 0.125f);
      const int base0 = l15 * 512 + (key0 >> 1) + 2 * g;  // pair index
      *reinterpret_cast<uint2*>(&Plds[(unsigned)base0 ^ sw]) = u0;
      *reinterpret_cast<uint2*>(&Plds[(unsigned)(base0 + 8) ^ sw]) = u1;
    }
  }
  __syncthreads();

  // ---- phase 2: per-row modulate+softmax; float4 streams, 2-deep pipeline --
  {
    const float4* sbase = reinterpret_cast<const float4*>(
        sph + ((size_t)bh << 20) + (((size_t)(it * 16)) << 10));
    float4 svbuf[2][4];
#pragma unroll
    for (int i = 0; i < 4; ++i)
      svbuf[0][i] = sbase[(size_t)(w * 4) * 256 + lane + 64 * i];
#pragma unroll
    for (int rr = 0; rr < 4; ++rr) {
      const int row = w * 4 + rr;
      if (rr < 3) {
#pragma unroll
        for (int i = 0; i < 4; ++i)
          svbuf[(rr + 1) & 1][i] = sbase[(size_t)(row + 1) * 256 + lane + 64 * i];
      }
      const unsigned rsw = (unsigned)((row & 7) << 2);
      const int lbase = row * 512;
      // LDS raw logits: uint2 at even pair index 2*lane+128*i.
      // rsw has bit0==0 so XOR preserves pair-evenness (8B-aligned uint2).
      uint2 uv[4];
#pragma unroll
      for (int i = 0; i < 4; ++i)
        uv[i] = *reinterpret_cast<uint2*>(
            &Plds[(unsigned)(lbase + 2 * lane + 128 * i) ^ rsw]);
      float va[16];
#pragma unroll
      for (int i = 0; i < 4; ++i) {
        const float4 sv = svbuf[rr & 1][i];
        va[4 * i + 0] = f16lo(uv[i].x) * sv.x;
        va[4 * i + 1] = f16hi(uv[i].x) * sv.y;
        va[4 * i + 2] = f16lo(uv[i].y) * sv.z;
        va[4 * i + 3] = f16hi(uv[i].y) * sv.w;
      }
      float m = va[0];
#pragma unroll
      for (int i = 1; i < 16; ++i) m = fmaxf(m, va[i]);
#pragma unroll
      for (int off = 1; off < 64; off <<= 1) m = fmaxf(m, __shfl_xor(m, off));
      float sum = 0.f;
#pragma unroll
      for (int i = 0; i < 16; ++i) {
        va[i] = __expf(va[i] - m);
        sum += va[i];
      }
#pragma unroll
      for (int off = 1; off < 64; off <<= 1) sum += __shfl_xor(sum, off);
      const float inv = 1.f / sum;
      float4* po = reinterpret_cast<float4*>(Pout + ((size_t)bh << 20) +
                                             (((size_t)(it * 16 + row)) << 10));
#pragma unroll
      for (int i = 0; i < 4; ++i) {
        float4 p;
        p.x = va[4 * i + 0] * inv;
        p.y = va[4 * i + 1] * inv;
        p.z = va[4 * i + 2] * inv;
        p.w = va[4 * i + 3] * inv;
        po[lane + 64 * i] = p;
        uint2 pb;
        pb.x = packbf(p.x, p.y);
        pb.y = packbf(p.z, p.w);
        *reinterpret_cast<uint2*>(
            &Plds[(unsigned)(lbase + 2 * lane + 128 * i) ^ rsw]) = pb;
      }
    }
  }
  __syncthreads();

  // ---- phase 3: PV, batches of 8 (8 KB in flight) ----
  {
    const int c0 = w * 16;
    f32x4 o0 = {0.f, 0.f, 0.f, 0.f};
    const __hip_bfloat16* vb =
        VT + (size_t)bh * DK_ * S_ + (size_t)(c0 + l15) * S_ + 8 * g;
#pragma unroll
    for (int kb2 = 0; kb2 < 4; ++kb2) {
      bf16x8 vreg[8];
      bf16x8 preg[8];
#pragma unroll
      for (int u = 0; u < 8; ++u)
        vreg[u] = *reinterpret_cast<const bf16x8*>(vb + kb2 * 256 + u * 32);
#pragma unroll
      for (int u = 0; u < 8; ++u) {
        const int k0 = kb2 * 256 + u * 32;
        preg[u] = *reinterpret_cast<const bf16x8*>(
            &Plds[(unsigned)(l15 * 512 + (k0 >> 1) + 4 * g) ^ sw]);
      }
      __builtin_amdgcn_s_setprio(1);
#pragma unroll
      for (int u = 0; u < 8; ++u) o0 = MFMA16(preg[u], vreg[u], o0);
      __builtin_amdgcn_s_setprio(0);
    }
    const int b = bh >> 4, h = bh & 15;
#pragma unroll
    for (int r = 0; r < 4; ++r) {
      const int srow = it * 16 + 4 * g + r;
      O[((size_t)(b * S_ + srow)) * D_ + h * DK_ + c0 + l15] = __float2bfloat16(o0[r]);
    }
  }
}

// ---------------------------------------------------------------------------
// LayerNorm over D, write [S,B,D]
// ---------------------------------------------------------------------------
__global__ __launch_bounds__(256) void k_ln(const float* __restrict__ Z,
                                            const float* __restrict__ gamma,
                                            const float* __restrict__ beta,
                                            float* __restrict__ out) {
  const int r = blockIdx.x;  // b*S+s
  const int b = r >> 10, s = r & 1023;
  const int tid = threadIdx.x;
  const float4 z = *reinterpret_cast<const float4*>(Z + (size_t)r * D_ + (tid << 2));
  float sum = z.x + z.y + z.z + z.w;
  float sq = z.x * z.x + z.y * z.y + z.z * z.z + z.w * z.w;
#pragma unroll
  for (int off = 1; off < 64; off <<= 1) {
    sum += __shfl_xor(sum, off);
    sq += __shfl_xor(sq, off);
  }
  __shared__ float rs[4];
  __shared__ float rq[4];
  const int wv = tid >> 6, ln = tid & 63;
  if (ln == 0) { rs[wv] = sum; rq[wv] = sq; }
  __syncthreads();
  const float tsum = rs[0] + rs[1] + rs[2] + rs[3];
  const float tsq = rq[0] + rq[1] + rq[2] + rq[3];
  const float mu = tsum * (1.0f / 1024.0f);
  const float var = tsq * (1.0f / 1024.0f) - mu * mu;
  const float rstd = rsqrtf(var + 1e-6f);
  const float4 gm = *reinterpret_cast<const float4*>(gamma + (tid << 2));
  const float4 bt = *reinterpret_cast<const float4*>(beta + (tid << 2));
  float4 o;
  o.x = (z.x - mu) * rstd * gm.x + bt.x;
  o.y = (z.y - mu) * rstd * gm.y + bt.y;
  o.z = (z.z - mu) * rstd * gm.z + bt.z;
  o.w = (z.w - mu) * rstd * gm.w + bt.w;
  *reinterpret_cast<float4*>(out + (size_t)(s * B_ + b) * D_ + (tid << 2)) = o;
}

extern "C" void kernel_launch(void* const* d_in, const int* in_sizes, int n_in,
                              void* d_out, int out_size, void* d_ws, size_t ws_size,
                              hipStream_t stream) {
  const float* q = (const float*)d_in[0];
  const float* k = (const float*)d_in[1];
  const float* v = (const float*)d_in[2];
  const float* sph = (const float*)d_in[3];
  const float* Wq = (const float*)d_in[4];
  const float* Wk = (const float*)d_in[5];
  const float* Wv = (const float*)d_in[6];
  const float* Wo = (const float*)d_in[7];
  const float* gamma = (const float*)d_in[8];
  const float* beta = (const float*)d_in[9];

  float* out = (float*)d_out;                 // [S,B,D]
  float* P = out + (size_t)4 * 1024 * 1024;   // [B,H,S,S]

  char* ws = (char*)d_ws;
  __hip_bfloat16* xq = (__hip_bfloat16*)(ws);                        // 8MB [S*B][D]
  __hip_bfloat16* xk = (__hip_bfloat16*)(ws + ((size_t)8 << 20));    // 8MB
  __hip_bfloat16* xv = (__hip_bfloat16*)(ws + ((size_t)16 << 20));   // 8MB
  __hip_bfloat16* wqb = (__hip_bfloat16*)(ws + ((size_t)24 << 20));  // 2MB
  __hip_bfloat16* wkb = (__hip_bfloat16*)(ws + ((size_t)26 << 20));
  __hip_bfloat16* wvb = (__hip_bfloat16*)(ws + ((size_t)28 << 20));
  __hip_bfloat16* wob = (__hip_bfloat16*)(ws + ((size_t)30 << 20));
  __hip_bfloat16* Qh = (__hip_bfloat16*)(ws + ((size_t)32 << 20));   // 8MB [bh][s][dk]
  __hip_bfloat16* Khb = (__hip_bfloat16*)(ws + ((size_t)40 << 20));  // 8MB [bh][s][dk]
  __hip_bfloat16* VTb = (__hip_bfloat16*)(ws + ((size_t)48 << 20));  // 8MB [bh][dk][s]
  __hip_bfloat16* Ob = (__hip_bfloat16*)(ws + ((size_t)56 << 20));   // 8MB [B][S][D]
  float* Z = (float*)(ws + ((size_t)64 << 20));                      // 16MB [B][S][D]

  const dim3 blk(256);
  k_cvt3<<<12288, blk, 0, stream>>>(q, k, v, xq, xk, xv);
  k_cvt4<<<4096, blk, 0, stream>>>(Wq, Wk, Wv, Wo, wqb, wkb, wvb, wob);

  k_gemm<0><<<dim3(32, 16), blk, 0, stream>>>(xq, wqb, nullptr, Qh, nullptr);
  k_gemm<0><<<dim3(32, 16), blk, 0, stream>>>(xk, wkb, nullptr, Khb, nullptr);
  k_gemm<1><<<dim3(32, 16), blk, 0, stream>>>(xv, wvb, nullptr, VTb, nullptr);

  k_attn<<<dim3(64, 64), blk, 0, stream>>>(Qh, Khb, VTb, sph, P, Ob);

  k_gemm<2><<<dim3(32, 16), blk, 0, stream>>>(Ob, wob, q, nullptr, Z);
  k_ln<<<4096, blk, 0, stream>>>(Z, gamma, beta, out);
}

// Round 9
// 282.840 us; speedup vs baseline: 1.2118x; 1.0118x over previous
//
#include <hip/hip_runtime.h>
#include <hip/hip_bf16.h>
#include <hip/hip_fp16.h>
#include <cstdint>

// Dims
constexpr int B_ = 4, H_ = 16, S_ = 1024, D_ = 1024, DK_ = 64;

typedef __bf16 bf16x8 __attribute__((ext_vector_type(8)));
typedef float f32x4 __attribute__((ext_vector_type(4)));
#define MFMA16(a, b, c) __builtin_amdgcn_mfma_f32_16x16x32_bf16(a, b, c, 0, 0, 0)

static __device__ inline unsigned short f2bf(float f) {
  __hip_bfloat16 h = __float2bfloat16(f);
  return *reinterpret_cast<unsigned short*>(&h);
}
static __device__ inline unsigned packbf(float lo, float hi) {
  return ((unsigned)f2bf(hi) << 16) | (unsigned)f2bf(lo);
}
static __device__ inline unsigned pack_f16(float x, float y) {
  __half hx = __float2half(x), hy = __float2half(y);
  return ((unsigned)(*reinterpret_cast<unsigned short*>(&hy)) << 16) |
         (unsigned)(*reinterpret_cast<unsigned short*>(&hx));
}
static __device__ inline float f16lo(unsigned u) {
  unsigned short s = (unsigned short)(u & 0xffff);
  return __half2float(*reinterpret_cast<__half*>(&s));
}
static __device__ inline float f16hi(unsigned u) {
  unsigned short s = (unsigned short)(u >> 16);
  return __half2float(*reinterpret_cast<__half*>(&s));
}

// ---------------------------------------------------------------------------
// f32 -> bf16 conversions, fused launches
// ---------------------------------------------------------------------------
__global__ __launch_bounds__(256) void k_cvt3(const float* __restrict__ x0,
                                              const float* __restrict__ x1,
                                              const float* __restrict__ x2,
                                              __hip_bfloat16* __restrict__ y0,
                                              __hip_bfloat16* __restrict__ y1,
                                              __hip_bfloat16* __restrict__ y2) {
  const int sel = blockIdx.x >> 12;                       // 4096 blocks per tensor
  const int i = (blockIdx.x & 4095) * 256 + threadIdx.x;  // float4 index
  const float* x = sel == 0 ? x0 : (sel == 1 ? x1 : x2);
  __hip_bfloat16* y = sel == 0 ? y0 : (sel == 1 ? y1 : y2);
  const float4 v = reinterpret_cast<const float4*>(x)[i];
  ushort4 o;
  o.x = f2bf(v.x); o.y = f2bf(v.y); o.z = f2bf(v.z); o.w = f2bf(v.w);
  *reinterpret_cast<ushort4*>(&y[(size_t)i * 4]) = o;
}

__global__ __launch_bounds__(256) void k_cvt4(const float* __restrict__ x0,
                                              const float* __restrict__ x1,
                                              const float* __restrict__ x2,
                                              const float* __restrict__ x3,
                                              __hip_bfloat16* __restrict__ y0,
                                              __hip_bfloat16* __restrict__ y1,
                                              __hip_bfloat16* __restrict__ y2,
                                              __hip_bfloat16* __restrict__ y3) {
  const int sel = blockIdx.x >> 10;                       // 1024 blocks per tensor
  const int i = (blockIdx.x & 1023) * 256 + threadIdx.x;  // float4 index
  const float* x = sel == 0 ? x0 : (sel == 1 ? x1 : (sel == 2 ? x2 : x3));
  __hip_bfloat16* y = sel == 0 ? y0 : (sel == 1 ? y1 : (sel == 2 ? y2 : y3));
  const float4 v = reinterpret_cast<const float4*>(x)[i];
  ushort4 o;
  o.x = f2bf(v.x); o.y = f2bf(v.y); o.z = f2bf(v.z); o.w = f2bf(v.w);
  *reinterpret_cast<ushort4*>(&y[(size_t)i * 4]) = o;
}

// ---------------------------------------------------------------------------
// bf16 MFMA GEMM (unchanged)
// ---------------------------------------------------------------------------
template <int MODE>
__global__ __launch_bounds__(256) void k_gemm(const __hip_bfloat16* __restrict__ A,
                                              const __hip_bfloat16* __restrict__ Bw,
                                              const float* __restrict__ resid,
                                              __hip_bfloat16* __restrict__ Yb,
                                              float* __restrict__ Yf) {
  __shared__ __hip_bfloat16 Als[128 * 64];
  __shared__ __hip_bfloat16 Bls[64 * 64];
  const int tid = threadIdx.x;
  const int lane = tid & 63;
  const int l15 = lane & 15, g = lane >> 4;
  const int w = tid >> 6;
  const int wr = w >> 1, wc = w & 1;
  const int rt = blockIdx.x, ct = blockIdx.y;
  f32x4 acc[4][2] = {};

  for (int k0 = 0; k0 < D_; k0 += 64) {
#pragma unroll
    for (int q = 0; q < 4; ++q) {
      const int slot0 = q * 256 + (tid & 192);
      const int slot = slot0 + lane;
      const int r = slot >> 3, p = slot & 7;
      const int lc = p ^ (r & 7);
      const __hip_bfloat16* src = A + (size_t)(rt * 128 + r) * D_ + k0 + lc * 8;
      __builtin_amdgcn_global_load_lds(
          (const __attribute__((address_space(1))) unsigned int*)src,
          (__attribute__((address_space(3))) unsigned int*)&Als[slot0 * 8], 16, 0, 0);
    }
#pragma unroll
    for (int q = 0; q < 2; ++q) {
      const int slot0 = q * 256 + (tid & 192);
      const int slot = slot0 + lane;
      const int r = slot >> 3, p = slot & 7;
      const int lc = p ^ (r & 7);
      const __hip_bfloat16* src = Bw + (size_t)(ct * 64 + r) * D_ + k0 + lc * 8;
      __builtin_amdgcn_global_load_lds(
          (const __attribute__((address_space(1))) unsigned int*)src,
          (__attribute__((address_space(3))) unsigned int*)&Bls[slot0 * 8], 16, 0, 0);
    }
    __syncthreads();
#pragma unroll
    for (int ks = 0; ks < 2; ++ks) {
      bf16x8 bfr[2];
#pragma unroll
      for (int cf = 0; cf < 2; ++cf) {
        const int r = wc * 32 + cf * 16 + l15;
        const int p = (ks * 4 + g) ^ (r & 7);
        bfr[cf] = *reinterpret_cast<const bf16x8*>(&Bls[(r * 8 + p) * 8]);
      }
#pragma unroll
      for (int fi = 0; fi < 4; ++fi) {
        const int r = wr * 64 + fi * 16 + l15;
        const int p = (ks * 4 + g) ^ (r & 7);
        const bf16x8 af = *reinterpret_cast<const bf16x8*>(&Als[(r * 8 + p) * 8]);
        acc[fi][0] = MFMA16(af, bfr[0], acc[fi][0]);
        acc[fi][1] = MFMA16(af, bfr[1], acc[fi][1]);
      }
    }
    __syncthreads();
  }
#pragma unroll
  for (int fi = 0; fi < 4; ++fi)
#pragma unroll
    for (int cf = 0; cf < 2; ++cf)
#pragma unroll
      for (int r = 0; r < 4; ++r) {
        const int m = rt * 128 + wr * 64 + fi * 16 + 4 * g + r;
        const int t = wc * 32 + cf * 16 + l15;
        const float val = acc[fi][cf][r];
        if (MODE == 0) {
          const int s = m >> 2, b = m & 3;
          Yb[((size_t)((b * H_ + ct) * S_ + s)) * DK_ + t] = __float2bfloat16(val);
        } else if (MODE == 1) {
          const int s = m >> 2, b = m & 3;
          Yb[((size_t)((b * H_ + ct) * DK_ + t)) * S_ + s] = __float2bfloat16(val);
        } else {
          const int b = m >> 10, s = m & 1023;
          const int o = ct * 64 + t;
          Yf[(size_t)m * D_ + o] = val + resid[(size_t)(s * B_ + b) * D_ + o];
        }
      }
}

// ---------------------------------------------------------------------------
// Fused attention with EARLY sph STREAM ISSUE (T14 async-stage split):
// The wave's rows 0-1 sph loads (8x float4) are issued at kernel entry and
// pinned there by sched_barrier(0); they drain once at the first K-use
// (vmcnt FIFO), then phases 1-2 run with sph already in registers. Rows 2-3
// are issued mid-row-0 softmax (hidden behind the row-0/1 reduce chains).
// P1: 2-deep K pipeline; raw qk/8 -> f16 pairs in LDS.
// P2: per-row modulate+softmax; float4 P stores (fire-and-forget).
// P3: PV in batches of 8.
// ---------------------------------------------------------------------------
__global__ __launch_bounds__(256, 4) void k_attn(const __hip_bfloat16* __restrict__ Qh,
                                                 const __hip_bfloat16* __restrict__ Kh,
                                                 const __hip_bfloat16* __restrict__ VT,
                                                 const float* __restrict__ sph,
                                                 float* __restrict__ Pout,
                                                 __hip_bfloat16* __restrict__ O) {
  __shared__ unsigned int Plds[16 * 512];  // 32KB
  const int tid = threadIdx.x, lane = tid & 63, w = tid >> 6;
  const int l15 = lane & 15, g = lane >> 4;
  const int it = blockIdx.x, bh = blockIdx.y;
  const unsigned sw = (unsigned)((l15 & 7) << 2);
  const int wrow = w * 4;  // this wave's first softmax row

  const float4* sbase = reinterpret_cast<const float4*>(
      sph + ((size_t)bh << 20) + (((size_t)(it * 16)) << 10));
  float4 sv0[4], sv1[4], sv2[4], sv3[4];
  // ---- phase 0: issue rows 0-1 sph stream NOW; pin with sched_barrier ----
#pragma unroll
  for (int i = 0; i < 4; ++i) sv0[i] = sbase[(size_t)(wrow + 0) * 256 + lane + 64 * i];
#pragma unroll
  for (int i = 0; i < 4; ++i) sv1[i] = sbase[(size_t)(wrow + 1) * 256 + lane + 64 * i];
  __builtin_amdgcn_sched_barrier(0);

  // ---- phase 1: raw logits; 2-deep K pipeline ----
  {
    const __hip_bfloat16* qp = Qh + ((size_t)bh * S_ + it * 16 + l15) * DK_ + 8 * g;
    const bf16x8 qf0 = *reinterpret_cast<const bf16x8*>(qp);
    const bf16x8 qf1 = *reinterpret_cast<const bf16x8*>(qp + 32);
    const __hip_bfloat16* kb0 =
        Kh + (size_t)bh * S_ * DK_ + (size_t)(w * 256 + l15) * DK_ + 8 * g;
    bf16x8 kra[2], krb[2], krc[2], krd[2];
    kra[0] = *reinterpret_cast<const bf16x8*>(kb0);
    krb[0] = *reinterpret_cast<const bf16x8*>(kb0 + 32);
    krc[0] = *reinterpret_cast<const bf16x8*>(kb0 + 16 * DK_);
    krd[0] = *reinterpret_cast<const bf16x8*>(kb0 + 16 * DK_ + 32);
#pragma unroll
    for (int j = 0; j < 8; ++j) {
      const int cur = j & 1, nxt = cur ^ 1;
      if (j < 7) {
        const __hip_bfloat16* kp = kb0 + (size_t)(j + 1) * 32 * DK_;
        kra[nxt] = *reinterpret_cast<const bf16x8*>(kp);
        krb[nxt] = *reinterpret_cast<const bf16x8*>(kp + 32);
        krc[nxt] = *reinterpret_cast<const bf16x8*>(kp + 16 * DK_);
        krd[nxt] = *reinterpret_cast<const bf16x8*>(kp + 16 * DK_ + 32);
      }
      f32x4 a0 = {0.f, 0.f, 0.f, 0.f};
      f32x4 a1 = {0.f, 0.f, 0.f, 0.f};
      __builtin_amdgcn_s_setprio(1);
      a0 = MFMA16(kra[cur], qf0, a0);
      a0 = MFMA16(krb[cur], qf1, a0);
      a1 = MFMA16(krc[cur], qf0, a1);
      a1 = MFMA16(krd[cur], qf1, a1);
      __builtin_amdgcn_s_setprio(0);
      const int key0 = w * 256 + j * 32;
      uint2 u0, u1;
      u0.x = pack_f16(a0[0] * 0.125f, a0[1] * 0.125f);
      u0.y = pack_f16(a0[2] * 0.125f, a0[3] * 0.125f);
      u1.x = pack_f16(a1[0] * 0.125f, a1[1] * 0.125f);
      u1.y = pack_f16(a1[2] * 0.125f, a1[3] * 0.125f);
      const int base0 = l15 * 512 + (key0 >> 1) + 2 * g;  // pair index
      *reinterpret_cast<uint2*>(&Plds[(unsigned)base0 ^ sw]) = u0;
      *reinterpret_cast<uint2*>(&Plds[(unsigned)(base0 + 8) ^ sw]) = u1;
    }
  }
  __syncthreads();

  // ---- phase 2: per-row modulate+softmax; sph already in registers ----
  {
    auto rowtail = [&](int rr, float va[16]) {
      const int row = wrow + rr;
      float m = va[0];
#pragma unroll
      for (int i = 1; i < 16; ++i) m = fmaxf(m, va[i]);
#pragma unroll
      for (int off = 1; off < 64; off <<= 1) m = fmaxf(m, __shfl_xor(m, off));
      float sum = 0.f;
#pragma unroll
      for (int i = 0; i < 16; ++i) {
        va[i] = __expf(va[i] - m);
        sum += va[i];
      }
#pragma unroll
      for (int off = 1; off < 64; off <<= 1) sum += __shfl_xor(sum, off);
      const float inv = 1.f / sum;
      const unsigned rsw = (unsigned)((row & 7) << 2);
      const int lbase = row * 512;
      float4* po = reinterpret_cast<float4*>(Pout + ((size_t)bh << 20) +
                                             (((size_t)(it * 16 + row)) << 10));
#pragma unroll
      for (int i = 0; i < 4; ++i) {
        float4 p;
        p.x = va[4 * i + 0] * inv;
        p.y = va[4 * i + 1] * inv;
        p.z = va[4 * i + 2] * inv;
        p.w = va[4 * i + 3] * inv;
        po[lane + 64 * i] = p;
        uint2 pb;
        pb.x = packbf(p.x, p.y);
        pb.y = packbf(p.z, p.w);
        *reinterpret_cast<uint2*>(
            &Plds[(unsigned)(lbase + 2 * lane + 128 * i) ^ rsw]) = pb;
      }
    };
    auto ldlogits = [&](int rr, uint2 uv[4]) {
      const int row = wrow + rr;
      const unsigned rsw = (unsigned)((row & 7) << 2);
      const int lbase = row * 512;
#pragma unroll
      for (int i = 0; i < 4; ++i)
        uv[i] = *reinterpret_cast<uint2*>(
            &Plds[(unsigned)(lbase + 2 * lane + 128 * i) ^ rsw]);
    };
    auto mkva = [&](uint2 uv[4], float4 sv[4], float va[16]) {
#pragma unroll
      for (int i = 0; i < 4; ++i) {
        va[4 * i + 0] = f16lo(uv[i].x) * sv[i].x;
        va[4 * i + 1] = f16hi(uv[i].x) * sv[i].y;
        va[4 * i + 2] = f16lo(uv[i].y) * sv[i].z;
        va[4 * i + 3] = f16hi(uv[i].y) * sv[i].w;
      }
    };
    // row 0: after consuming sv0, issue rows 2-3 stream (hidden by reduces)
    {
      uint2 uv[4];
      float va[16];
      ldlogits(0, uv);
      mkva(uv, sv0, va);
#pragma unroll
      for (int i = 0; i < 4; ++i) sv2[i] = sbase[(size_t)(wrow + 2) * 256 + lane + 64 * i];
#pragma unroll
      for (int i = 0; i < 4; ++i) sv3[i] = sbase[(size_t)(wrow + 3) * 256 + lane + 64 * i];
      __builtin_amdgcn_sched_barrier(0);
      rowtail(0, va);
    }
    {
      uint2 uv[4];
      float va[16];
      ldlogits(1, uv);
      mkva(uv, sv1, va);
      rowtail(1, va);
    }
    {
      uint2 uv[4];
      float va[16];
      ldlogits(2, uv);
      mkva(uv, sv2, va);
      rowtail(2, va);
    }
    {
      uint2 uv[4];
      float va[16];
      ldlogits(3, uv);
      mkva(uv, sv3, va);
      rowtail(3, va);
    }
  }
  __syncthreads();

  // ---- phase 3: PV, batches of 8 (8 KB in flight) ----
  {
    const int c0 = w * 16;
    f32x4 o0 = {0.f, 0.f, 0.f, 0.f};
    const __hip_bfloat16* vb =
        VT + (size_t)bh * DK_ * S_ + (size_t)(c0 + l15) * S_ + 8 * g;
#pragma unroll
    for (int kb2 = 0; kb2 < 4; ++kb2) {
      bf16x8 vreg[8];
      bf16x8 preg[8];
#pragma unroll
      for (int u = 0; u < 8; ++u)
        vreg[u] = *reinterpret_cast<const bf16x8*>(vb + kb2 * 256 + u * 32);
#pragma unroll
      for (int u = 0; u < 8; ++u) {
        const int k0 = kb2 * 256 + u * 32;
        preg[u] = *reinterpret_cast<const bf16x8*>(
            &Plds[(unsigned)(l15 * 512 + (k0 >> 1) + 4 * g) ^ sw]);
      }
      __builtin_amdgcn_s_setprio(1);
#pragma unroll
      for (int u = 0; u < 8; ++u) o0 = MFMA16(preg[u], vreg[u], o0);
      __builtin_amdgcn_s_setprio(0);
    }
    const int b = bh >> 4, h = bh & 15;
#pragma unroll
    for (int r = 0; r < 4; ++r) {
      const int srow = it * 16 + 4 * g + r;
      O[((size_t)(b * S_ + srow)) * D_ + h * DK_ + c0 + l15] = __float2bfloat16(o0[r]);
    }
  }
}

// ---------------------------------------------------------------------------
// LayerNorm over D, write [S,B,D]
// ---------------------------------------------------------------------------
__global__ __launch_bounds__(256) void k_ln(const float* __restrict__ Z,
                                            const float* __restrict__ gamma,
                                            const float* __restrict__ beta,
                                            float* __restrict__ out) {
  const int r = blockIdx.x;  // b*S+s
  const int b = r >> 10, s = r & 1023;
  const int tid = threadIdx.x;
  const float4 z = *reinterpret_cast<const float4*>(Z + (size_t)r * D_ + (tid << 2));
  float sum = z.x + z.y + z.z + z.w;
  float sq = z.x * z.x + z.y * z.y + z.z * z.z + z.w * z.w;
#pragma unroll
  for (int off = 1; off < 64; off <<= 1) {
    sum += __shfl_xor(sum, off);
    sq += __shfl_xor(sq, off);
  }
  __shared__ float rs[4];
  __shared__ float rq[4];
  const int wv = tid >> 6, ln = tid & 63;
  if (ln == 0) { rs[wv] = sum; rq[wv] = sq; }
  __syncthreads();
  const float tsum = rs[0] + rs[1] + rs[2] + rs[3];
  const float tsq = rq[0] + rq[1] + rq[2] + rq[3];
  const float mu = tsum * (1.0f / 1024.0f);
  const float var = tsq * (1.0f / 1024.0f) - mu * mu;
  const float rstd = rsqrtf(var + 1e-6f);
  const float4 gm = *reinterpret_cast<const float4*>(gamma + (tid << 2));
  const float4 bt = *reinterpret_cast<const float4*>(beta + (tid << 2));
  float4 o;
  o.x = (z.x - mu) * rstd * gm.x + bt.x;
  o.y = (z.y - mu) * rstd * gm.y + bt.y;
  o.z = (z.z - mu) * rstd * gm.z + bt.z;
  o.w = (z.w - mu) * rstd * gm.w + bt.w;
  *reinterpret_cast<float4*>(out + (size_t)(s * B_ + b) * D_ + (tid << 2)) = o;
}

extern "C" void kernel_launch(void* const* d_in, const int* in_sizes, int n_in,
                              void* d_out, int out_size, void* d_ws, size_t ws_size,
                              hipStream_t stream) {
  const float* q = (const float*)d_in[0];
  const float* k = (const float*)d_in[1];
  const float* v = (const float*)d_in[2];
  const float* sph = (const float*)d_in[3];
  const float* Wq = (const float*)d_in[4];
  const float* Wk = (const float*)d_in[5];
  const float* Wv = (const float*)d_in[6];
  const float* Wo = (const float*)d_in[7];
  const float* gamma = (const float*)d_in[8];
  const float* beta = (const float*)d_in[9];

  float* out = (float*)d_out;                 // [S,B,D]
  float* P = out + (size_t)4 * 1024 * 1024;   // [B,H,S,S]

  char* ws = (char*)d_ws;
  __hip_bfloat16* xq = (__hip_bfloat16*)(ws);                        // 8MB [S*B][D]
  __hip_bfloat16* xk = (__hip_bfloat16*)(ws + ((size_t)8 << 20));    // 8MB
  __hip_bfloat16* xv = (__hip_bfloat16*)(ws + ((size_t)16 << 20));   // 8MB
  __hip_bfloat16* wqb = (__hip_bfloat16*)(ws + ((size_t)24 << 20));  // 2MB
  __hip_bfloat16* wkb = (__hip_bfloat16*)(ws + ((size_t)26 << 20));
  __hip_bfloat16* wvb = (__hip_bfloat16*)(ws + ((size_t)28 << 20));
  __hip_bfloat16* wob = (__hip_bfloat16*)(ws + ((size_t)30 << 20));
  __hip_bfloat16* Qh = (__hip_bfloat16*)(ws + ((size_t)32 << 20));   // 8MB [bh][s][dk]
  __hip_bfloat16* Khb = (__hip_bfloat16*)(ws + ((size_t)40 << 20));  // 8MB [bh][s][dk]
  __hip_bfloat16* VTb = (__hip_bfloat16*)(ws + ((size_t)48 << 20));  // 8MB [bh][dk][s]
  __hip_bfloat16* Ob = (__hip_bfloat16*)(ws + ((size_t)56 << 20));   // 8MB [B][S][D]
  float* Z = (float*)(ws + ((size_t)64 << 20));                      // 16MB [B][S][D]

  const dim3 blk(256);
  k_cvt3<<<12288, blk, 0, stream>>>(q, k, v, xq, xk, xv);
  k_cvt4<<<4096, blk, 0, stream>>>(Wq, Wk, Wv, Wo, wqb, wkb, wvb, wob);

  k_gemm<0><<<dim3(32, 16), blk, 0, stream>>>(xq, wqb, nullptr, Qh, nullptr);
  k_gemm<0><<<dim3(32, 16), blk, 0, stream>>>(xk, wkb, nullptr, Khb, nullptr);
  k_gemm<1><<<dim3(32, 16), blk, 0, stream>>>(xv, wvb, nullptr, VTb, nullptr);

  k_attn<<<dim3(64, 64), blk, 0, stream>>>(Qh, Khb, VTb, sph, P, Ob);

  k_gemm<2><<<dim3(32, 16), blk, 0, stream>>>(Ob, wob, q, nullptr, Z);
  k_ln<<<4096, blk, 0, stream>>>(Z, gamma, beta, out);
}